// Round 16
// baseline (107.137 us; speedup 1.0000x reference)
//
#include <hip/hip_runtime.h>
#include <hip/hip_bf16.h>

#define EPS 1e-3f
// 1/sqrt(32) * log2(e): scores come out of QK^T already in log2-space
#define QSC_LOG2E 0.2550348653f

typedef __attribute__((ext_vector_type(8))) short bf16x8;
typedef __attribute__((ext_vector_type(4))) float f32x4;
typedef __attribute__((ext_vector_type(4))) unsigned short u16x4;
typedef __attribute__((ext_vector_type(8))) unsigned short u16x8;
typedef __attribute__((ext_vector_type(2))) unsigned int u32x2;

typedef const __attribute__((address_space(1))) unsigned int g_u32;
typedef __attribute__((address_space(3))) unsigned int l_u32;

__device__ __forceinline__ unsigned short f2bf(float f) {
    union { float f; unsigned u; } v; v.f = f;
    unsigned r = v.u + 0x7FFFu + ((v.u >> 16) & 1u);
    return (unsigned short)(r >> 16);
}
__device__ __forceinline__ float bf2f(unsigned short h) {
    union { unsigned u; float f; } v; v.u = ((unsigned)h) << 16;
    return v.f;
}
__device__ __forceinline__ unsigned pkbf(float lo, float hi) {
    float2 t; t.x = lo; t.y = hi;
    __hip_bfloat162 h = __float22bfloat162_rn(t);
    union { __hip_bfloat162 h; unsigned u; } c; c.h = h;
    return c.u;
}

// ---------- fused: weights->bf16 (blocks 0..191) + x transpose (blocks 192..991) ----------
__global__ __launch_bounds__(256) void conv_kernel(
    const float* __restrict__ wq, const float* __restrict__ wc,
    unsigned short* __restrict__ wqb, unsigned short* __restrict__ wcb,
    const float* __restrict__ x, unsigned short* __restrict__ xt)
{
    int bid = blockIdx.x;
    int tid = threadIdx.x;
    if (bid < 192) {
        int i = (bid * 256 + tid) * 4;
        const float* src; unsigned short* dst; int off;
        if (i < 131072) { src = wq; dst = wqb; off = i; }
        else            { src = wc; dst = wcb; off = i - 131072; }
        f32x4 v = *(const f32x4*)(src + off);
        u16x4 o;
        #pragma unroll
        for (int j = 0; j < 4; ++j) o[j] = f2bf(v[j]);
        *(u16x4*)(dst + off) = o;
        return;
    }
    __shared__ float t[64][65];
    int bid2 = bid - 192;
    int l0 = (bid2 % 25) * 64, c0 = ((bid2 / 25) & 3) * 64, b = bid2 / 100;
    const float* xb = x + ((size_t)b * 256 + c0) * 1600 + l0;
    #pragma unroll
    for (int p = 0; p < 4; ++p) {
        int row = p * 16 + (tid >> 4);
        int col = (tid & 15) * 4;
        f32x4 v = *(const f32x4*)(xb + (size_t)row * 1600 + col);
        #pragma unroll
        for (int j = 0; j < 4; ++j) t[row][col + j] = v[j];
    }
    __syncthreads();
    int l = tid >> 2, cs = tid & 3;
    u16x8 o0, o1;
    #pragma unroll
    for (int i = 0; i < 8; ++i) o0[i] = f2bf(t[cs * 16 + i][l]);
    #pragma unroll
    for (int i = 0; i < 8; ++i) o1[i] = f2bf(t[cs * 16 + 8 + i][l]);
    unsigned short* dst = xt + ((size_t)b * 1600 + l0 + l) * 256 + c0 + cs * 16;
    *(u16x8*)dst = o0;
    *(u16x8*)(dst + 8) = o1;
}

// ---------- qkv = BN(qkv_w @ x) via MFMA, 32o x 64l per wave ----------
// grid 832 (XCD-pinned): o_tile = bid/104, gl_tile = bid%104 (<100).
__global__ __launch_bounds__(256) void qkv_gemm_kernel(
    const unsigned short* __restrict__ wqb, const unsigned short* __restrict__ xt,
    const float* __restrict__ gg, const float* __restrict__ bet,
    const float* __restrict__ mm, const float* __restrict__ vv,
    unsigned short* __restrict__ qk, unsigned short* __restrict__ vt,
    unsigned short* __restrict__ v2)
{
    __shared__ unsigned short ldsT[4][32 * 72];   // per-wave transpose tile [d_loc][l_loc]

    const int gl_tile = blockIdx.x % 104;
    const int by = blockIdx.x / 104;
    if (gl_tile >= 100) return;                   // safe: no barriers in this kernel

    const int tid = threadIdx.x, wid = tid >> 6, lane = tid & 63;
    const int g = lane >> 4, cc = lane & 15;
    const int gl0 = gl_tile * 128 + (wid & 1) * 64;
    const int o_base = by * 64 + (wid >> 1) * 32;

    const unsigned short* wb0 = wqb + (size_t)(o_base + cc) * 256;
    const unsigned short* wb1 = wqb + (size_t)(o_base + 16 + cc) * 256;
    const unsigned short* xb  = xt + (size_t)(gl0 + cc) * 256;

    const f32x4 fz = {0.f, 0.f, 0.f, 0.f};
    f32x4 acc[2][4] = {{fz, fz, fz, fz}, {fz, fz, fz, fz}};
    #pragma unroll 4
    for (int kk = 0; kk < 256; kk += 32) {
        bf16x8 a0 = *(const bf16x8*)(wb0 + kk + 8 * g);
        bf16x8 a1 = *(const bf16x8*)(wb1 + kk + 8 * g);
        #pragma unroll
        for (int f = 0; f < 4; ++f) {
            bf16x8 bfr = *(const bf16x8*)(xb + (size_t)f * 16 * 256 + kk + 8 * g);
            acc[0][f] = __builtin_amdgcn_mfma_f32_16x16x32_bf16(a0, bfr, acc[0][f], 0, 0, 0);
            acc[1][f] = __builtin_amdgcn_mfma_f32_16x16x32_bf16(a1, bfr, acc[1][f], 0, 0, 0);
        }
    }

    const int head = by >> 1;
    const bool is_v = by & 1;
    float inv[2][4], bias[2][4];
    #pragma unroll
    for (int i = 0; i < 2; ++i) {
        #pragma unroll
        for (int r = 0; r < 4; ++r) {
            int oc = o_base + 16 * i + 4 * g + r;
            float iv = gg[oc] * rsqrtf(vv[oc] + EPS);
            float bs = bet[oc] - mm[oc] * iv;
            if ((oc & 127) < 32) { iv *= QSC_LOG2E; bs *= QSC_LOG2E; }
            inv[i][r] = iv; bias[i][r] = bs;
        }
    }

    if (!is_v) {
        #pragma unroll
        for (int f = 0; f < 4; ++f) {
            int gl = gl0 + 16 * f + cc;
            int b  = gl / 1600;
            int ll = gl - b * 1600;
            unsigned short* dst = qk + ((size_t)(b * 4 + head) * 1600 + ll) * 64;
            #pragma unroll
            for (int i = 0; i < 2; ++i) {
                u16x4 pk;
                #pragma unroll
                for (int r = 0; r < 4; ++r) pk[r] = f2bf(acc[i][f][r] * inv[i][r] + bias[i][r]);
                *(u16x4*)(dst + (o_base & 63) + 16 * i + 4 * g) = pk;
            }
        }
    } else {
        const int d_base = (o_base & 63);
        // v2 (channel-major) stores + LDS transpose writes
        #pragma unroll
        for (int f = 0; f < 4; ++f) {
            int gl = gl0 + 16 * f + cc;
            unsigned short* v2dst = v2 + (size_t)gl * 256 + head * 64 + d_base;
            #pragma unroll
            for (int i = 0; i < 2; ++i) {
                u16x4 pk;
                #pragma unroll
                for (int r = 0; r < 4; ++r) {
                    unsigned short h = f2bf(acc[i][f][r] * inv[i][r] + bias[i][r]);
                    pk[r] = h;
                    ldsT[wid][(16 * i + 4 * g + r) * 72 + 16 * f + cc] = h;
                }
                *(u16x4*)(v2dst + 16 * i + 4 * g) = pk;
            }
        }
        asm volatile("s_waitcnt lgkmcnt(0)" ::: "memory");
        // coalesced vt stores: [d][l] rows, u16x8 per lane
        #pragma unroll
        for (int j = 0; j < 4; ++j) {
            int p = j * 64 + lane;
            int d_loc = p >> 3, c8 = p & 7;
            u16x8 val = *(const u16x8*)&ldsT[wid][d_loc * 72 + c8 * 8];
            int gl_c = gl0 + c8 * 8;
            int b  = gl_c / 1600;
            int ll = gl_c - b * 1600;
            *(u16x8*)(vt + ((size_t)(b * 4 + head) * 64 + d_base + d_loc) * 1600 + ll) = val;
        }
    }
}

// ---------- flash attention: 2 q-groups per wave, K-split, XCD-pinned, counted vmcnt ----------
// grid 832: combo = bid&63 (pair*2+z), qsuper = bid>>6 (13 supers of 128 q; super 12
// covers 64 q -> group-2 clamped/guarded). Block 256 = 4 waves x 16q x 2 groups.
// Each wave's 12 LDS fragment reads serve BOTH q-groups (halved LDS-pipe load).
__global__ __launch_bounds__(256) void attn_kernel(
    const unsigned short* __restrict__ qk, const unsigned short* __restrict__ vt,
    unsigned short* __restrict__ pa, unsigned short* __restrict__ pb,
    float* __restrict__ ssum)
{
    __shared__ __align__(16) unsigned short kbuf[2][64 * 32];  // [t][d], chunk^=(t&3)
    __shared__ __align__(16) unsigned short vbuf[2][64 * 64];  // [d][t], chunk^=(d&7)

    const int tid = threadIdx.x, wid = tid >> 6, lane = tid & 63;
    const int g = lane >> 4, cc = lane & 15;
    const int combo = blockIdx.x & 63;
    const int pair = combo >> 1;
    const int z = combo & 1;
    const int qsuper = blockIdx.x >> 6;
    const int q0 = qsuper * 128 + wid * 16;
    const bool two = (qsuper < 12);
    const int q0b = two ? (q0 + 64) : q0;

    const int kt_begin = z ? 13 : 0;
    const int NT = z ? 12 : 13;

    const unsigned short* qkb = qk + (size_t)pair * 1600 * 64;
    const unsigned short* vtb = vt + (size_t)pair * 64 * 1600;

    bf16x8 bq0 = *(const bf16x8*)(qkb + (size_t)(q0 + cc) * 64 + 8 * g);
    bf16x8 bq1 = *(const bf16x8*)(qkb + (size_t)(q0b + cc) * 64 + 8 * g);

    // persistent staging source pointers (advance by constants per tile)
    const int krow = tid >> 2, kchk = tid & 3;
    const unsigned short* kP = qkb + (size_t)krow * 64 + 32 + (kchk ^ (krow & 3)) * 8
                              + (size_t)kt_begin * 4096;
    const int vrow = tid >> 3, vchk = tid & 7;
    const unsigned short* vPa = vtb + (size_t)vrow * 1600 + (vchk ^ (vrow & 7)) * 8
                              + (size_t)kt_begin * 64;
    const unsigned short* vPb = vPa + (size_t)32 * 1600;

    // precomputed LDS fragment base addresses (immediate offsets inside compute)
    const unsigned short* kr0  = &kbuf[0][cc * 32 + (g ^ (cc & 3)) * 8];
    const unsigned short* kr1  = &kbuf[1][cc * 32 + (g ^ (cc & 3)) * 8];
    const unsigned short* vr0a = &vbuf[0][cc * 64 + ((g) ^ (cc & 7)) * 8];
    const unsigned short* vr0b = &vbuf[0][cc * 64 + ((4 + g) ^ (cc & 7)) * 8];
    const unsigned short* vr1a = &vbuf[1][cc * 64 + ((g) ^ (cc & 7)) * 8];
    const unsigned short* vr1b = &vbuf[1][cc * 64 + ((4 + g) ^ (cc & 7)) * 8];

    #define STAGE(bufi)                                                               \
        do {                                                                          \
            __builtin_amdgcn_global_load_lds((g_u32*)kP,                              \
                (l_u32*)(&kbuf[bufi][wid * 512]), 16, 0, 0);                          \
            __builtin_amdgcn_global_load_lds((g_u32*)vPa,                             \
                (l_u32*)(&vbuf[bufi][wid * 512]), 16, 0, 0);                          \
            __builtin_amdgcn_global_load_lds((g_u32*)vPb,                             \
                (l_u32*)(&vbuf[bufi][2048 + wid * 512]), 16, 0, 0);                   \
            kP += 4096; vPa += 64; vPb += 64;                                         \
        } while (0)

    const f32x4 fz = {0.f, 0.f, 0.f, 0.f};
    const short one_bf = (short)0x3F80;
    const bf16x8 ones = {one_bf, one_bf, one_bf, one_bf, one_bf, one_bf, one_bf, one_bf};
    f32x4 o[2][4] = {{fz, fz, fz, fz}, {fz, fz, fz, fz}};
    f32x4 sumacc[2] = {fz, fz};

    auto compute = [&](const unsigned short* kr, const unsigned short* vra,
                       const unsigned short* vrb) {
        // ---- QK^T for both q-groups (kf transient) ----
        f32x4 s4[2][4];
        {
            bf16x8 kf[4];
            #pragma unroll
            for (int f = 0; f < 4; ++f)
                kf[f] = *(const bf16x8*)(kr + f * 512);
            __builtin_amdgcn_s_setprio(1);
            #pragma unroll
            for (int f = 0; f < 4; ++f)
                s4[0][f] = __builtin_amdgcn_mfma_f32_16x16x32_bf16(kf[f], bq0, fz, 0, 0, 0);
            #pragma unroll
            for (int f = 0; f < 4; ++f)
                s4[1][f] = __builtin_amdgcn_mfma_f32_16x16x32_bf16(kf[f], bq1, fz, 0, 0, 0);
            __builtin_amdgcn_s_setprio(0);
        }

        // ---- exp2 (raw v_exp_f32) + pack + permlane transpose (per q-group) ----
        unsigned pb_u[2][2][4];
        #pragma unroll
        for (int qf = 0; qf < 2; ++qf) {
            unsigned c2[4][2];
            #pragma unroll
            for (int f = 0; f < 4; ++f) {
                float p0 = __builtin_amdgcn_exp2f(s4[qf][f][0]);
                float p1 = __builtin_amdgcn_exp2f(s4[qf][f][1]);
                float p2 = __builtin_amdgcn_exp2f(s4[qf][f][2]);
                float p3 = __builtin_amdgcn_exp2f(s4[qf][f][3]);
                c2[f][0] = pkbf(p0, p1);
                c2[f][1] = pkbf(p2, p3);
            }
            #pragma unroll
            for (int s2 = 0; s2 < 2; ++s2) {
                const int fA = 2 * s2, fB = 2 * s2 + 1;
                u32x2 xy0 = __builtin_amdgcn_permlane32_swap(c2[fA][0], c2[fB][0], false, false);
                u32x2 xy1 = __builtin_amdgcn_permlane32_swap(c2[fA][1], c2[fB][1], false, false);
                u32x2 w02 = __builtin_amdgcn_permlane16_swap(xy0.x, xy0.y, false, false);
                u32x2 w13 = __builtin_amdgcn_permlane16_swap(xy1.x, xy1.y, false, false);
                pb_u[qf][s2][0] = w02.x;
                pb_u[qf][s2][1] = w13.x;
                pb_u[qf][s2][2] = w02.y;
                pb_u[qf][s2][3] = w13.y;
            }
        }

        // ---- PV + row-sum-by-ones (vf transient per s2 half) ----
        __builtin_amdgcn_s_setprio(1);
        #pragma unroll
        for (int s2 = 0; s2 < 2; ++s2) {
            const unsigned short* vr = s2 ? vrb : vra;
            bf16x8 vf[4];
            #pragma unroll
            for (int f2 = 0; f2 < 4; ++f2)
                vf[f2] = *(const bf16x8*)(vr + f2 * 1024);
            #pragma unroll
            for (int qf = 0; qf < 2; ++qf) {
                union { unsigned u[4]; bf16x8 v; } pbv;
                #pragma unroll
                for (int j = 0; j < 4; ++j) pbv.u[j] = pb_u[qf][s2][j];
                #pragma unroll
                for (int f2 = 0; f2 < 4; ++f2)
                    o[qf][f2] = __builtin_amdgcn_mfma_f32_16x16x32_bf16(vf[f2], pbv.v, o[qf][f2], 0, 0, 0);
                sumacc[qf] = __builtin_amdgcn_mfma_f32_16x16x32_bf16(ones, pbv.v, sumacc[qf], 0, 0, 0);
            }
        }
        __builtin_amdgcn_s_setprio(0);
    };

    // prologue: first tile -> buf0
    STAGE(0);

    // counted-vmcnt pipeline (generic parity loop; handles odd NT)
    for (int t = 0; t + 1 < NT; ++t) {
        STAGE((t + 1) & 1);                              // stage tile t+1
        asm volatile("s_waitcnt vmcnt(3)" ::: "memory"); // tile t's stage done
        __builtin_amdgcn_s_barrier();
        if (t & 1) compute(kr1, vr1a, vr1b);
        else       compute(kr0, vr0a, vr0b);
        __builtin_amdgcn_s_barrier();                    // all waves done with buf t&1
    }
    asm volatile("s_waitcnt vmcnt(0)" ::: "memory");
    __builtin_amdgcn_s_barrier();
    if ((NT - 1) & 1) compute(kr1, vr1a, vr1b);
    else              compute(kr0, vr0a, vr0b);
    #undef STAGE

    // ---- epilogue: store UNNORMALIZED partial O + per-q sums (group 2 guarded) ----
    const int n = pair & 3, b = pair >> 2;
    {
        unsigned short* pdst = (z ? pb : pa) + ((size_t)b * 1600 + q0 + cc) * 256 + n * 64;
        #pragma unroll
        for (int f2 = 0; f2 < 4; ++f2) {
            u16x4 st;
            #pragma unroll
            for (int r = 0; r < 4; ++r) st[r] = f2bf(o[0][f2][r]);
            *(u16x4*)(pdst + 16 * f2 + 4 * g) = st;
        }
    }
    if (two) {
        unsigned short* pdst = (z ? pb : pa) + ((size_t)b * 1600 + q0b + cc) * 256 + n * 64;
        #pragma unroll
        for (int f2 = 0; f2 < 4; ++f2) {
            u16x4 st;
            #pragma unroll
            for (int r = 0; r < 4; ++r) st[r] = f2bf(o[1][f2][r]);
            *(u16x4*)(pdst + 16 * f2 + 4 * g) = st;
        }
    }
    if (lane < 16) {
        ssum[((size_t)z * 32 + b * 4 + n) * 1600 + q0 + cc] = sumacc[0][0];
        if (two)
            ssum[((size_t)z * 32 + b * 4 + n) * 1600 + q0b + cc] = sumacc[1][0];
    }
}

// ---------- fused: y = (pa+pb)/sum; y2 = y + BN(dw3x3(v)); out = BN(cb2_w @ y2) ----------
// grid (400): per block 32 gl x 256 c. dw -> LDS [32][264], GEMM from LDS.
__global__ __launch_bounds__(256) void dwout_kernel(
    const unsigned short* __restrict__ v2,
    const unsigned short* __restrict__ pa, const unsigned short* __restrict__ pb,
    const float* __restrict__ ssum,
    const float* __restrict__ cw, const float* __restrict__ g1,
    const float* __restrict__ b1, const float* __restrict__ m1,
    const float* __restrict__ v1,
    const unsigned short* __restrict__ wcb, const float* __restrict__ g2,
    const float* __restrict__ b2, const float* __restrict__ m2,
    const float* __restrict__ vbn2,
    float* __restrict__ out)
{
    __shared__ unsigned short y2s[32][264];   // row stride 528B -> 2-way (free) on B reads

    const int tid = threadIdx.x, wid = tid >> 6, lane = tid & 63;
    const int g = lane >> 4, cc = lane & 15;
    const int gl0 = blockIdx.x * 32;

    // ---- dw + combine phase: 8 c-parts x 32 gl rows ----
    {
        const int gl_loc = tid & 31, cpart = tid >> 5;
        const int gl = gl0 + gl_loc;
        const int b = gl / 1600, l = gl - b * 1600;
        const int h = l / 40, w = l - h * 40;
        #pragma unroll
        for (int cg = 0; cg < 4; ++cg) {
            const int c0 = cpart * 32 + cg * 8;
            const int n = c0 >> 6;
            float s0 = ssum[(size_t)(b * 4 + n) * 1600 + l];
            float s1 = ssum[(size_t)(32 + b * 4 + n) * 1600 + l];
            float il = 1.f / (s0 + s1);
            float s[8];
            #pragma unroll
            for (int i = 0; i < 8; ++i) s[i] = 0.f;
            #pragma unroll
            for (int kh = -1; kh <= 1; ++kh) {
                int hh = h + kh;
                if (hh < 0 || hh >= 40) continue;
                #pragma unroll
                for (int kw = -1; kw <= 1; ++kw) {
                    int ww = w + kw;
                    if (ww < 0 || ww >= 40) continue;
                    u16x8 vv8 = *(const u16x8*)(v2 + (size_t)(gl + kh * 40 + kw) * 256 + c0);
                    const int tap = (kh + 1) * 3 + (kw + 1);
                    #pragma unroll
                    for (int i = 0; i < 8; ++i)
                        s[i] = fmaf(bf2f(vv8[i]), cw[(c0 + i) * 9 + tap], s[i]);
                }
            }
            u16x8 ya = *(const u16x8*)(pa + (size_t)gl * 256 + c0);
            u16x8 yb = *(const u16x8*)(pb + (size_t)gl * 256 + c0);
            u16x8 o8;
            #pragma unroll
            for (int i = 0; i < 8; ++i) {
                int c = c0 + i;
                float iv = g1[c] * rsqrtf(v1[c] + EPS);
                float yv = (bf2f(ya[i]) + bf2f(yb[i])) * il;
                o8[i] = f2bf(yv + s[i] * iv + (b1[c] - m1[c] * iv));
            }
            *(u16x8*)&y2s[gl_loc][c0] = o8;
        }
    }
    __syncthreads();

    // ---- GEMM phase: wave wid owns o in [wid*64, wid*64+64) ----
    const int o_base = wid * 64;
    const unsigned short* wb = wcb + (size_t)(o_base + cc) * 256;

    const f32x4 fz = {0.f, 0.f, 0.f, 0.f};
    f32x4 acc[4][2] = {{fz, fz}, {fz, fz}, {fz, fz}, {fz, fz}};
    #pragma unroll 4
    for (int kk = 0; kk < 256; kk += 32) {
        bf16x8 a[4], bfr[2];
        #pragma unroll
        for (int i = 0; i < 4; ++i)
            a[i] = *(const bf16x8*)(wb + (size_t)i * 16 * 256 + kk + 8 * g);
        #pragma unroll
        for (int f = 0; f < 2; ++f)
            bfr[f] = *(const bf16x8*)&y2s[16 * f + cc][kk + 8 * g];
        #pragma unroll
        for (int i = 0; i < 4; ++i)
            #pragma unroll
            for (int f = 0; f < 2; ++f)
                acc[i][f] = __builtin_amdgcn_mfma_f32_16x16x32_bf16(a[i], bfr[f], acc[i][f], 0, 0, 0);
    }
    #pragma unroll
    for (int i = 0; i < 4; ++i) {
        #pragma unroll
        for (int r = 0; r < 4; ++r) {
            int oc = o_base + 16 * i + 4 * g + r;
            float iv = g2[oc] * rsqrtf(vbn2[oc] + EPS);
            float bs = b2[oc] - m2[oc] * iv;
            #pragma unroll
            for (int f = 0; f < 2; ++f) {
                int gl = gl0 + 16 * f + cc;
                int b  = gl / 1600;
                int ll = gl - b * 1600;
                out[((size_t)b * 256 + oc) * 1600 + ll] = acc[i][f][r] * iv + bs;
            }
        }
    }
}

extern "C" void kernel_launch(void* const* d_in, const int* in_sizes, int n_in,
                              void* d_out, int out_size, void* d_ws, size_t ws_size,
                              hipStream_t stream) {
    const float* x     = (const float*)d_in[0];
    const float* qkv_w = (const float*)d_in[1];
    const float* qkv_g = (const float*)d_in[2];
    const float* qkv_b = (const float*)d_in[3];
    const float* qkv_m = (const float*)d_in[4];
    const float* qkv_v = (const float*)d_in[5];
    const float* cb1_w = (const float*)d_in[6];
    const float* cb1_g = (const float*)d_in[7];
    const float* cb1_b = (const float*)d_in[8];
    const float* cb1_m = (const float*)d_in[9];
    const float* cb1_v = (const float*)d_in[10];
    const float* cb2_w = (const float*)d_in[11];
    const float* cb2_g = (const float*)d_in[12];
    const float* cb2_b = (const float*)d_in[13];
    const float* cb2_m = (const float*)d_in[14];
    const float* cb2_v = (const float*)d_in[15];
    float* out = (float*)d_out;

    unsigned short* ws16 = (unsigned short*)d_ws;
    const size_t N16 = 3276800;                 // 8*1600*256
    unsigned short* xt  = ws16;                 // [gl][256]; reused as pa after qkv
    unsigned short* qk  = ws16 + N16;           // [pair][l][64]
    unsigned short* vt  = ws16 + 2 * N16;       // [pair][d][l]
    unsigned short* pb_ = ws16 + 3 * N16;       // [gl][256] partial O (half 1)
    unsigned short* v2  = ws16 + 4 * N16;       // [gl][256] v channel-major
    unsigned short* wqb = ws16 + 5 * N16;       // 512*256
    unsigned short* wcb = wqb + 131072;         // 256*256
    float* ssum = (float*)(wcb + 65536);        // [2][8][4][1600]
    unsigned short* pa = xt;                    // alias (xt dead after qkv_gemm)

    conv_kernel<<<dim3(992), 256, 0, stream>>>(qkv_w, cb2_w, wqb, wcb, x, xt);
    qkv_gemm_kernel<<<dim3(832), 256, 0, stream>>>(wqb, xt, qkv_g, qkv_b, qkv_m, qkv_v, qk, vt, v2);
    attn_kernel<<<dim3(832), 256, 0, stream>>>(qk, vt, pa, pb_, ssum);
    dwout_kernel<<<dim3(400), 256, 0, stream>>>(v2, pa, pb_, ssum,
                                                cb1_w, cb1_g, cb1_b, cb1_m, cb1_v,
                                                wcb, cb2_g, cb2_b, cb2_m, cb2_v, out);
}

// Round 17
// 104.325 us; speedup vs baseline: 1.0270x; 1.0270x over previous
//
#include <hip/hip_runtime.h>
#include <hip/hip_bf16.h>

#define EPS 1e-3f
// 1/sqrt(32) * log2(e): scores come out of QK^T already in log2-space
#define QSC_LOG2E 0.2550348653f

typedef __attribute__((ext_vector_type(8))) short bf16x8;
typedef __attribute__((ext_vector_type(4))) float f32x4;
typedef __attribute__((ext_vector_type(4))) unsigned short u16x4;
typedef __attribute__((ext_vector_type(8))) unsigned short u16x8;
typedef __attribute__((ext_vector_type(2))) unsigned int u32x2;

typedef const __attribute__((address_space(1))) unsigned int g_u32;
typedef __attribute__((address_space(3))) unsigned int l_u32;

__device__ __forceinline__ unsigned short f2bf(float f) {
    union { float f; unsigned u; } v; v.f = f;
    unsigned r = v.u + 0x7FFFu + ((v.u >> 16) & 1u);
    return (unsigned short)(r >> 16);
}
__device__ __forceinline__ float bf2f(unsigned short h) {
    union { unsigned u; float f; } v; v.u = ((unsigned)h) << 16;
    return v.f;
}
__device__ __forceinline__ unsigned pkbf(float lo, float hi) {
    float2 t; t.x = lo; t.y = hi;
    __hip_bfloat162 h = __float22bfloat162_rn(t);
    union { __hip_bfloat162 h; unsigned u; } c; c.h = h;
    return c.u;
}

// ---------- fused: weights->bf16 (blocks 0..191) + x transpose (blocks 192..991) ----------
__global__ __launch_bounds__(256) void conv_kernel(
    const float* __restrict__ wq, const float* __restrict__ wc,
    unsigned short* __restrict__ wqb, unsigned short* __restrict__ wcb,
    const float* __restrict__ x, unsigned short* __restrict__ xt)
{
    int bid = blockIdx.x;
    int tid = threadIdx.x;
    if (bid < 192) {
        int i = (bid * 256 + tid) * 4;
        const float* src; unsigned short* dst; int off;
        if (i < 131072) { src = wq; dst = wqb; off = i; }
        else            { src = wc; dst = wcb; off = i - 131072; }
        f32x4 v = *(const f32x4*)(src + off);
        u16x4 o;
        #pragma unroll
        for (int j = 0; j < 4; ++j) o[j] = f2bf(v[j]);
        *(u16x4*)(dst + off) = o;
        return;
    }
    __shared__ float t[64][65];
    int bid2 = bid - 192;
    int l0 = (bid2 % 25) * 64, c0 = ((bid2 / 25) & 3) * 64, b = bid2 / 100;
    const float* xb = x + ((size_t)b * 256 + c0) * 1600 + l0;
    #pragma unroll
    for (int p = 0; p < 4; ++p) {
        int row = p * 16 + (tid >> 4);
        int col = (tid & 15) * 4;
        f32x4 v = *(const f32x4*)(xb + (size_t)row * 1600 + col);
        #pragma unroll
        for (int j = 0; j < 4; ++j) t[row][col + j] = v[j];
    }
    __syncthreads();
    int l = tid >> 2, cs = tid & 3;
    u16x8 o0, o1;
    #pragma unroll
    for (int i = 0; i < 8; ++i) o0[i] = f2bf(t[cs * 16 + i][l]);
    #pragma unroll
    for (int i = 0; i < 8; ++i) o1[i] = f2bf(t[cs * 16 + 8 + i][l]);
    unsigned short* dst = xt + ((size_t)b * 1600 + l0 + l) * 256 + c0 + cs * 16;
    *(u16x8*)dst = o0;
    *(u16x8*)(dst + 8) = o1;
}

// ---------- qkv = BN(qkv_w @ x) via MFMA, 32o x 64l per wave ----------
// grid 832 (XCD-pinned): o_tile = bid/104, gl_tile = bid%104 (<100).
__global__ __launch_bounds__(256) void qkv_gemm_kernel(
    const unsigned short* __restrict__ wqb, const unsigned short* __restrict__ xt,
    const float* __restrict__ gg, const float* __restrict__ bet,
    const float* __restrict__ mm, const float* __restrict__ vv,
    unsigned short* __restrict__ qk, unsigned short* __restrict__ vt,
    unsigned short* __restrict__ v2)
{
    __shared__ unsigned short ldsT[4][32 * 72];   // per-wave transpose tile [d_loc][l_loc]

    const int gl_tile = blockIdx.x % 104;
    const int by = blockIdx.x / 104;
    if (gl_tile >= 100) return;                   // safe: no barriers in this kernel

    const int tid = threadIdx.x, wid = tid >> 6, lane = tid & 63;
    const int g = lane >> 4, cc = lane & 15;
    const int gl0 = gl_tile * 128 + (wid & 1) * 64;
    const int o_base = by * 64 + (wid >> 1) * 32;

    const unsigned short* wb0 = wqb + (size_t)(o_base + cc) * 256;
    const unsigned short* wb1 = wqb + (size_t)(o_base + 16 + cc) * 256;
    const unsigned short* xb  = xt + (size_t)(gl0 + cc) * 256;

    const f32x4 fz = {0.f, 0.f, 0.f, 0.f};
    f32x4 acc[2][4] = {{fz, fz, fz, fz}, {fz, fz, fz, fz}};
    #pragma unroll 4
    for (int kk = 0; kk < 256; kk += 32) {
        bf16x8 a0 = *(const bf16x8*)(wb0 + kk + 8 * g);
        bf16x8 a1 = *(const bf16x8*)(wb1 + kk + 8 * g);
        #pragma unroll
        for (int f = 0; f < 4; ++f) {
            bf16x8 bfr = *(const bf16x8*)(xb + (size_t)f * 16 * 256 + kk + 8 * g);
            acc[0][f] = __builtin_amdgcn_mfma_f32_16x16x32_bf16(a0, bfr, acc[0][f], 0, 0, 0);
            acc[1][f] = __builtin_amdgcn_mfma_f32_16x16x32_bf16(a1, bfr, acc[1][f], 0, 0, 0);
        }
    }

    const int head = by >> 1;
    const bool is_v = by & 1;
    float inv[2][4], bias[2][4];
    #pragma unroll
    for (int i = 0; i < 2; ++i) {
        #pragma unroll
        for (int r = 0; r < 4; ++r) {
            int oc = o_base + 16 * i + 4 * g + r;
            float iv = gg[oc] * rsqrtf(vv[oc] + EPS);
            float bs = bet[oc] - mm[oc] * iv;
            if ((oc & 127) < 32) { iv *= QSC_LOG2E; bs *= QSC_LOG2E; }
            inv[i][r] = iv; bias[i][r] = bs;
        }
    }

    if (!is_v) {
        #pragma unroll
        for (int f = 0; f < 4; ++f) {
            int gl = gl0 + 16 * f + cc;
            int b  = gl / 1600;
            int ll = gl - b * 1600;
            unsigned short* dst = qk + ((size_t)(b * 4 + head) * 1600 + ll) * 64;
            #pragma unroll
            for (int i = 0; i < 2; ++i) {
                u16x4 pk;
                #pragma unroll
                for (int r = 0; r < 4; ++r) pk[r] = f2bf(acc[i][f][r] * inv[i][r] + bias[i][r]);
                *(u16x4*)(dst + (o_base & 63) + 16 * i + 4 * g) = pk;
            }
        }
    } else {
        const int d_base = (o_base & 63);
        // v2 (channel-major) stores + LDS transpose writes
        #pragma unroll
        for (int f = 0; f < 4; ++f) {
            int gl = gl0 + 16 * f + cc;
            unsigned short* v2dst = v2 + (size_t)gl * 256 + head * 64 + d_base;
            #pragma unroll
            for (int i = 0; i < 2; ++i) {
                u16x4 pk;
                #pragma unroll
                for (int r = 0; r < 4; ++r) {
                    unsigned short h = f2bf(acc[i][f][r] * inv[i][r] + bias[i][r]);
                    pk[r] = h;
                    ldsT[wid][(16 * i + 4 * g + r) * 72 + 16 * f + cc] = h;
                }
                *(u16x4*)(v2dst + 16 * i + 4 * g) = pk;
            }
        }
        asm volatile("s_waitcnt lgkmcnt(0)" ::: "memory");
        // coalesced vt stores: [d][l] rows, u16x8 per lane
        #pragma unroll
        for (int j = 0; j < 4; ++j) {
            int p = j * 64 + lane;
            int d_loc = p >> 3, c8 = p & 7;
            u16x8 val = *(const u16x8*)&ldsT[wid][d_loc * 72 + c8 * 8];
            int gl_c = gl0 + c8 * 8;
            int b  = gl_c / 1600;
            int ll = gl_c - b * 1600;
            *(u16x8*)(vt + ((size_t)(b * 4 + head) * 64 + d_base + d_loc) * 1600 + ll) = val;
        }
    }
}

// ---------- flash attention: block K-split, XCD-pinned combos, counted vmcnt ----------
// grid 1600: combo = bid&63 (pair*2+z), qt = bid>>6. 64%8==0 -> all 25 q-tiles
// of a combo land on XCD combo%8; per-XCD K/V/Q footprint ~3.2 MB (L2-resident).
__global__ __launch_bounds__(256) void attn_kernel(
    const unsigned short* __restrict__ qk, const unsigned short* __restrict__ vt,
    unsigned short* __restrict__ pa, unsigned short* __restrict__ pb,
    float* __restrict__ ssum)
{
    __shared__ __align__(16) unsigned short kbuf[2][64 * 32];  // [t][d], chunk^=(t&3)
    __shared__ __align__(16) unsigned short vbuf[2][64 * 64];  // [d][t], chunk^=(d&7)

    const int tid = threadIdx.x, wid = tid >> 6, lane = tid & 63;
    const int g = lane >> 4, cc = lane & 15;
    const int combo = blockIdx.x & 63;
    const int pair = combo >> 1;
    const int z = combo & 1;
    const int q0 = (blockIdx.x >> 6) * 64 + wid * 16;

    const int kt_begin = z ? 13 : 0;
    const int NT = z ? 12 : 13;

    const unsigned short* qkb = qk + (size_t)pair * 1600 * 64;
    const unsigned short* vtb = vt + (size_t)pair * 64 * 1600;

    bf16x8 bq = *(const bf16x8*)(qkb + (size_t)(q0 + cc) * 64 + 8 * g);

    // persistent staging source pointers (advance by constants per tile)
    const int krow = tid >> 2, kchk = tid & 3;
    const unsigned short* kP = qkb + (size_t)krow * 64 + 32 + (kchk ^ (krow & 3)) * 8
                              + (size_t)kt_begin * 4096;
    const int vrow = tid >> 3, vchk = tid & 7;
    const unsigned short* vPa = vtb + (size_t)vrow * 1600 + (vchk ^ (vrow & 7)) * 8
                              + (size_t)kt_begin * 64;
    const unsigned short* vPb = vPa + (size_t)32 * 1600;

    // precomputed LDS fragment base addresses (immediate offsets inside compute)
    const unsigned short* kr0  = &kbuf[0][cc * 32 + (g ^ (cc & 3)) * 8];
    const unsigned short* kr1  = &kbuf[1][cc * 32 + (g ^ (cc & 3)) * 8];
    const unsigned short* vr0a = &vbuf[0][cc * 64 + ((g) ^ (cc & 7)) * 8];
    const unsigned short* vr0b = &vbuf[0][cc * 64 + ((4 + g) ^ (cc & 7)) * 8];
    const unsigned short* vr1a = &vbuf[1][cc * 64 + ((g) ^ (cc & 7)) * 8];
    const unsigned short* vr1b = &vbuf[1][cc * 64 + ((4 + g) ^ (cc & 7)) * 8];

    #define STAGE(bufi)                                                               \
        do {                                                                          \
            __builtin_amdgcn_global_load_lds((g_u32*)kP,                              \
                (l_u32*)(&kbuf[bufi][wid * 512]), 16, 0, 0);                          \
            __builtin_amdgcn_global_load_lds((g_u32*)vPa,                             \
                (l_u32*)(&vbuf[bufi][wid * 512]), 16, 0, 0);                          \
            __builtin_amdgcn_global_load_lds((g_u32*)vPb,                             \
                (l_u32*)(&vbuf[bufi][2048 + wid * 512]), 16, 0, 0);                   \
            kP += 4096; vPa += 64; vPb += 64;                                         \
        } while (0)

    const f32x4 fz = {0.f, 0.f, 0.f, 0.f};
    const short one_bf = (short)0x3F80;
    const bf16x8 ones = {one_bf, one_bf, one_bf, one_bf, one_bf, one_bf, one_bf, one_bf};
    f32x4 o[4] = {fz, fz, fz, fz};
    f32x4 sumacc = fz;

    auto compute = [&](const unsigned short* kr, const unsigned short* vra,
                       const unsigned short* vrb) {
        bf16x8 kf[4], vf[8];
        #pragma unroll
        for (int f = 0; f < 4; ++f)
            kf[f] = *(const bf16x8*)(kr + f * 512);
        #pragma unroll
        for (int f2 = 0; f2 < 4; ++f2) {
            vf[2 * f2]     = *(const bf16x8*)(vra + f2 * 1024);
            vf[2 * f2 + 1] = *(const bf16x8*)(vrb + f2 * 1024);
        }

        // ---- QK^T ----
        f32x4 s4[4];
        __builtin_amdgcn_s_setprio(1);
        #pragma unroll
        for (int f = 0; f < 4; ++f)
            s4[f] = __builtin_amdgcn_mfma_f32_16x16x32_bf16(kf[f], bq, fz, 0, 0, 0);
        __builtin_amdgcn_s_setprio(0);

        // ---- exp2 (raw v_exp_f32) + pack + permlane transpose ----
        unsigned c2[4][2];
        #pragma unroll
        for (int f = 0; f < 4; ++f) {
            float p0 = __builtin_amdgcn_exp2f(s4[f][0]);
            float p1 = __builtin_amdgcn_exp2f(s4[f][1]);
            float p2 = __builtin_amdgcn_exp2f(s4[f][2]);
            float p3 = __builtin_amdgcn_exp2f(s4[f][3]);
            c2[f][0] = pkbf(p0, p1);
            c2[f][1] = pkbf(p2, p3);
        }
        unsigned pb_u[2][4];
        #pragma unroll
        for (int s2 = 0; s2 < 2; ++s2) {
            const int fA = 2 * s2, fB = 2 * s2 + 1;
            u32x2 xy0 = __builtin_amdgcn_permlane32_swap(c2[fA][0], c2[fB][0], false, false);
            u32x2 xy1 = __builtin_amdgcn_permlane32_swap(c2[fA][1], c2[fB][1], false, false);
            u32x2 w02 = __builtin_amdgcn_permlane16_swap(xy0.x, xy0.y, false, false);
            u32x2 w13 = __builtin_amdgcn_permlane16_swap(xy1.x, xy1.y, false, false);
            pb_u[s2][0] = w02.x;
            pb_u[s2][1] = w13.x;
            pb_u[s2][2] = w02.y;
            pb_u[s2][3] = w13.y;
        }

        // ---- PV + row-sum-by-ones ----
        __builtin_amdgcn_s_setprio(1);
        #pragma unroll
        for (int s2 = 0; s2 < 2; ++s2) {
            union { unsigned u[4]; bf16x8 v; } pbv;
            #pragma unroll
            for (int j = 0; j < 4; ++j) pbv.u[j] = pb_u[s2][j];
            #pragma unroll
            for (int f2 = 0; f2 < 4; ++f2)
                o[f2] = __builtin_amdgcn_mfma_f32_16x16x32_bf16(vf[f2 * 2 + s2], pbv.v, o[f2], 0, 0, 0);
            sumacc = __builtin_amdgcn_mfma_f32_16x16x32_bf16(ones, pbv.v, sumacc, 0, 0, 0);
        }
        __builtin_amdgcn_s_setprio(0);
    };

    // prologue: first tile -> buf0
    STAGE(0);

    // counted-vmcnt pipeline (generic parity loop; handles odd NT)
    for (int t = 0; t + 1 < NT; ++t) {
        STAGE((t + 1) & 1);                              // stage tile t+1
        asm volatile("s_waitcnt vmcnt(3)" ::: "memory"); // tile t's stage done
        __builtin_amdgcn_s_barrier();
        if (t & 1) compute(kr1, vr1a, vr1b);
        else       compute(kr0, vr0a, vr0b);
        __builtin_amdgcn_s_barrier();                    // all waves done with buf t&1
    }
    asm volatile("s_waitcnt vmcnt(0)" ::: "memory");
    __builtin_amdgcn_s_barrier();
    if ((NT - 1) & 1) compute(kr1, vr1a, vr1b);
    else              compute(kr0, vr0a, vr0b);
    #undef STAGE

    // ---- epilogue: store UNNORMALIZED partial O + per-q sums ----
    const int n = pair & 3, b = pair >> 2;
    unsigned short* pdst = (z ? pb : pa) + ((size_t)b * 1600 + q0 + cc) * 256 + n * 64;
    #pragma unroll
    for (int f2 = 0; f2 < 4; ++f2) {
        u16x4 st;
        #pragma unroll
        for (int r = 0; r < 4; ++r) st[r] = f2bf(o[f2][r]);
        *(u16x4*)(pdst + 16 * f2 + 4 * g) = st;
    }
    if (lane < 16)
        ssum[((size_t)z * 32 + b * 4 + n) * 1600 + q0 + cc] = sumacc[0];
}

// ---------- fused: y = (pa+pb)/sum; y2 = y + BN(dw3x3(v)); out = BN(cb2_w @ y2) ----------
// grid (400): per block 32 gl x 256 c. dw -> LDS [32][264], GEMM from LDS.
__global__ __launch_bounds__(256) void dwout_kernel(
    const unsigned short* __restrict__ v2,
    const unsigned short* __restrict__ pa, const unsigned short* __restrict__ pb,
    const float* __restrict__ ssum,
    const float* __restrict__ cw, const float* __restrict__ g1,
    const float* __restrict__ b1, const float* __restrict__ m1,
    const float* __restrict__ v1,
    const unsigned short* __restrict__ wcb, const float* __restrict__ g2,
    const float* __restrict__ b2, const float* __restrict__ m2,
    const float* __restrict__ vbn2,
    float* __restrict__ out)
{
    __shared__ unsigned short y2s[32][264];   // row stride 528B -> 2-way (free) on B reads

    const int tid = threadIdx.x, wid = tid >> 6, lane = tid & 63;
    const int g = lane >> 4, cc = lane & 15;
    const int gl0 = blockIdx.x * 32;

    // ---- dw + combine phase: 8 c-parts x 32 gl rows ----
    {
        const int gl_loc = tid & 31, cpart = tid >> 5;
        const int gl = gl0 + gl_loc;
        const int b = gl / 1600, l = gl - b * 1600;
        const int h = l / 40, w = l - h * 40;
        #pragma unroll
        for (int cg = 0; cg < 4; ++cg) {
            const int c0 = cpart * 32 + cg * 8;
            const int n = c0 >> 6;
            float s0 = ssum[(size_t)(b * 4 + n) * 1600 + l];
            float s1 = ssum[(size_t)(32 + b * 4 + n) * 1600 + l];
            float il = 1.f / (s0 + s1);
            float s[8];
            #pragma unroll
            for (int i = 0; i < 8; ++i) s[i] = 0.f;
            #pragma unroll
            for (int kh = -1; kh <= 1; ++kh) {
                int hh = h + kh;
                if (hh < 0 || hh >= 40) continue;
                #pragma unroll
                for (int kw = -1; kw <= 1; ++kw) {
                    int ww = w + kw;
                    if (ww < 0 || ww >= 40) continue;
                    u16x8 vv8 = *(const u16x8*)(v2 + (size_t)(gl + kh * 40 + kw) * 256 + c0);
                    const int tap = (kh + 1) * 3 + (kw + 1);
                    #pragma unroll
                    for (int i = 0; i < 8; ++i)
                        s[i] = fmaf(bf2f(vv8[i]), cw[(c0 + i) * 9 + tap], s[i]);
                }
            }
            u16x8 ya = *(const u16x8*)(pa + (size_t)gl * 256 + c0);
            u16x8 yb = *(const u16x8*)(pb + (size_t)gl * 256 + c0);
            u16x8 o8;
            #pragma unroll
            for (int i = 0; i < 8; ++i) {
                int c = c0 + i;
                float iv = g1[c] * rsqrtf(v1[c] + EPS);
                float yv = (bf2f(ya[i]) + bf2f(yb[i])) * il;
                o8[i] = f2bf(yv + s[i] * iv + (b1[c] - m1[c] * iv));
            }
            *(u16x8*)&y2s[gl_loc][c0] = o8;
        }
    }
    __syncthreads();

    // ---- GEMM phase: wave wid owns o in [wid*64, wid*64+64) ----
    const int o_base = wid * 64;
    const unsigned short* wb = wcb + (size_t)(o_base + cc) * 256;

    const f32x4 fz = {0.f, 0.f, 0.f, 0.f};
    f32x4 acc[4][2] = {{fz, fz}, {fz, fz}, {fz, fz}, {fz, fz}};
    #pragma unroll 4
    for (int kk = 0; kk < 256; kk += 32) {
        bf16x8 a[4], bfr[2];
        #pragma unroll
        for (int i = 0; i < 4; ++i)
            a[i] = *(const bf16x8*)(wb + (size_t)i * 16 * 256 + kk + 8 * g);
        #pragma unroll
        for (int f = 0; f < 2; ++f)
            bfr[f] = *(const bf16x8*)&y2s[16 * f + cc][kk + 8 * g];
        #pragma unroll
        for (int i = 0; i < 4; ++i)
            #pragma unroll
            for (int f = 0; f < 2; ++f)
                acc[i][f] = __builtin_amdgcn_mfma_f32_16x16x32_bf16(a[i], bfr[f], acc[i][f], 0, 0, 0);
    }
    #pragma unroll
    for (int i = 0; i < 4; ++i) {
        #pragma unroll
        for (int r = 0; r < 4; ++r) {
            int oc = o_base + 16 * i + 4 * g + r;
            float iv = g2[oc] * rsqrtf(vbn2[oc] + EPS);
            float bs = b2[oc] - m2[oc] * iv;
            #pragma unroll
            for (int f = 0; f < 2; ++f) {
                int gl = gl0 + 16 * f + cc;
                int b  = gl / 1600;
                int ll = gl - b * 1600;
                out[((size_t)b * 256 + oc) * 1600 + ll] = acc[i][f][r] * iv + bs;
            }
        }
    }
}

extern "C" void kernel_launch(void* const* d_in, const int* in_sizes, int n_in,
                              void* d_out, int out_size, void* d_ws, size_t ws_size,
                              hipStream_t stream) {
    const float* x     = (const float*)d_in[0];
    const float* qkv_w = (const float*)d_in[1];
    const float* qkv_g = (const float*)d_in[2];
    const float* qkv_b = (const float*)d_in[3];
    const float* qkv_m = (const float*)d_in[4];
    const float* qkv_v = (const float*)d_in[5];
    const float* cb1_w = (const float*)d_in[6];
    const float* cb1_g = (const float*)d_in[7];
    const float* cb1_b = (const float*)d_in[8];
    const float* cb1_m = (const float*)d_in[9];
    const float* cb1_v = (const float*)d_in[10];
    const float* cb2_w = (const float*)d_in[11];
    const float* cb2_g = (const float*)d_in[12];
    const float* cb2_b = (const float*)d_in[13];
    const float* cb2_m = (const float*)d_in[14];
    const float* cb2_v = (const float*)d_in[15];
    float* out = (float*)d_out;

    unsigned short* ws16 = (unsigned short*)d_ws;
    const size_t N16 = 3276800;                 // 8*1600*256
    unsigned short* xt  = ws16;                 // [gl][256]; reused as pa after qkv
    unsigned short* qk  = ws16 + N16;           // [pair][l][64]
    unsigned short* vt  = ws16 + 2 * N16;       // [pair][d][l]
    unsigned short* pb_ = ws16 + 3 * N16;       // [gl][256] partial O (half 1)
    unsigned short* v2  = ws16 + 4 * N16;       // [gl][256] v channel-major
    unsigned short* wqb = ws16 + 5 * N16;       // 512*256
    unsigned short* wcb = wqb + 131072;         // 256*256
    float* ssum = (float*)(wcb + 65536);        // [2][8][4][1600]
    unsigned short* pa = xt;                    // alias (xt dead after qkv_gemm)

    conv_kernel<<<dim3(992), 256, 0, stream>>>(qkv_w, cb2_w, wqb, wcb, x, xt);
    qkv_gemm_kernel<<<dim3(832), 256, 0, stream>>>(wqb, xt, qkv_g, qkv_b, qkv_m, qkv_v, qk, vt, v2);
    attn_kernel<<<dim3(1600), 256, 0, stream>>>(qk, vt, pa, pb_, ssum);
    dwout_kernel<<<dim3(400), 256, 0, stream>>>(v2, pa, pb_, ssum,
                                                cb1_w, cb1_g, cb1_b, cb1_m, cb1_v,
                                                wcb, cb2_g, cb2_b, cb2_m, cb2_v, out);
}

// Round 18
// 102.066 us; speedup vs baseline: 1.0497x; 1.0221x over previous
//
#include <hip/hip_runtime.h>
#include <hip/hip_bf16.h>

#define EPS 1e-3f
// 1/sqrt(32) * log2(e): scores come out of QK^T already in log2-space
#define QSC_LOG2E 0.2550348653f

typedef __attribute__((ext_vector_type(8))) short bf16x8;
typedef __attribute__((ext_vector_type(4))) float f32x4;
typedef __attribute__((ext_vector_type(4))) unsigned short u16x4;
typedef __attribute__((ext_vector_type(8))) unsigned short u16x8;
typedef __attribute__((ext_vector_type(2))) unsigned int u32x2;

typedef const __attribute__((address_space(1))) unsigned int g_u32;
typedef __attribute__((address_space(3))) unsigned int l_u32;

__device__ __forceinline__ unsigned short f2bf(float f) {
    union { float f; unsigned u; } v; v.f = f;
    unsigned r = v.u + 0x7FFFu + ((v.u >> 16) & 1u);
    return (unsigned short)(r >> 16);
}
__device__ __forceinline__ float bf2f(unsigned short h) {
    union { unsigned u; float f; } v; v.u = ((unsigned)h) << 16;
    return v.f;
}
__device__ __forceinline__ unsigned pkbf(float lo, float hi) {
    float2 t; t.x = lo; t.y = hi;
    __hip_bfloat162 h = __float22bfloat162_rn(t);
    union { __hip_bfloat162 h; unsigned u; } c; c.h = h;
    return c.u;
}

// ---------- fused: weights->bf16 (0..191) + BN tables (992) + x transpose (192..991) ----------
__global__ __launch_bounds__(256) void conv_kernel(
    const float* __restrict__ wq, const float* __restrict__ wc,
    unsigned short* __restrict__ wqb, unsigned short* __restrict__ wcb,
    const float* __restrict__ x, unsigned short* __restrict__ xt,
    const float* __restrict__ qg, const float* __restrict__ qb,
    const float* __restrict__ qm, const float* __restrict__ qv,
    const float* __restrict__ c1w, const float* __restrict__ c1g,
    const float* __restrict__ c1b, const float* __restrict__ c1m,
    const float* __restrict__ c1v,
    const float* __restrict__ c2g, const float* __restrict__ c2b,
    const float* __restrict__ c2m, const float* __restrict__ c2v,
    float* __restrict__ tab)
{
    int bid = blockIdx.x;
    int tid = threadIdx.x;
    if (bid < 192) {
        int i = (bid * 256 + tid) * 4;
        const float* src; unsigned short* dst; int off;
        if (i < 131072) { src = wq; dst = wqb; off = i; }
        else            { src = wc; dst = wcb; off = i - 131072; }
        f32x4 v = *(const f32x4*)(src + off);
        u16x4 o;
        #pragma unroll
        for (int j = 0; j < 4; ++j) o[j] = f2bf(v[j]);
        *(u16x4*)(dst + off) = o;
        return;
    }
    if (bid == 992) {
        // BN tables: ivq[512], bsq[512], cwf[2304], bs1[256], iv2t[256], bs2t[256]
        float* ivq  = tab;
        float* bsq  = tab + 512;
        float* cwf  = tab + 1024;
        float* bs1  = tab + 3328;
        float* iv2t = tab + 3584;
        float* bs2t = tab + 3840;
        for (int o = tid; o < 512; o += 256) {
            float iv = qg[o] * rsqrtf(qv[o] + EPS);
            float bs = qb[o] - qm[o] * iv;
            if ((o & 127) < 32) { iv *= QSC_LOG2E; bs *= QSC_LOG2E; }
            ivq[o] = iv; bsq[o] = bs;
        }
        {
            int c = tid;
            float iv1 = c1g[c] * rsqrtf(c1v[c] + EPS);
            bs1[c] = c1b[c] - c1m[c] * iv1;
            #pragma unroll
            for (int t = 0; t < 9; ++t) cwf[c * 9 + t] = c1w[c * 9 + t] * iv1;
            float iv2 = c2g[c] * rsqrtf(c2v[c] + EPS);
            iv2t[c] = iv2;
            bs2t[c] = c2b[c] - c2m[c] * iv2;
        }
        return;
    }
    __shared__ float t[64][65];
    int bid2 = bid - 192;
    int l0 = (bid2 % 25) * 64, c0 = ((bid2 / 25) & 3) * 64, b = bid2 / 100;
    const float* xb = x + ((size_t)b * 256 + c0) * 1600 + l0;
    #pragma unroll
    for (int p = 0; p < 4; ++p) {
        int row = p * 16 + (tid >> 4);
        int col = (tid & 15) * 4;
        f32x4 v = *(const f32x4*)(xb + (size_t)row * 1600 + col);
        #pragma unroll
        for (int j = 0; j < 4; ++j) t[row][col + j] = v[j];
    }
    __syncthreads();
    int l = tid >> 2, cs = tid & 3;
    u16x8 o0, o1;
    #pragma unroll
    for (int i = 0; i < 8; ++i) o0[i] = f2bf(t[cs * 16 + i][l]);
    #pragma unroll
    for (int i = 0; i < 8; ++i) o1[i] = f2bf(t[cs * 16 + 8 + i][l]);
    unsigned short* dst = xt + ((size_t)b * 1600 + l0 + l) * 256 + c0 + cs * 16;
    *(u16x8*)dst = o0;
    *(u16x8*)(dst + 8) = o1;
}

// ---------- qkv = BN(qkv_w @ x) via MFMA, 32o x 64l per wave ----------
// grid 832 (XCD-pinned): o_tile = bid/104, gl_tile = bid%104 (<100).
__global__ __launch_bounds__(256) void qkv_gemm_kernel(
    const unsigned short* __restrict__ wqb, const unsigned short* __restrict__ xt,
    const float* __restrict__ tab,
    unsigned short* __restrict__ qk, unsigned short* __restrict__ vt,
    unsigned short* __restrict__ v2)
{
    __shared__ unsigned short ldsT[4][32 * 72];   // per-wave transpose tile [d_loc][l_loc]

    const int gl_tile = blockIdx.x % 104;
    const int by = blockIdx.x / 104;
    if (gl_tile >= 100) return;                   // safe: no barriers before this point

    const float* ivq = tab;
    const float* bsq = tab + 512;

    const int tid = threadIdx.x, wid = tid >> 6, lane = tid & 63;
    const int g = lane >> 4, cc = lane & 15;
    const int gl0 = gl_tile * 128 + (wid & 1) * 64;
    const int o_base = by * 64 + (wid >> 1) * 32;

    const unsigned short* wb0 = wqb + (size_t)(o_base + cc) * 256;
    const unsigned short* wb1 = wqb + (size_t)(o_base + 16 + cc) * 256;
    const unsigned short* xb  = xt + (size_t)(gl0 + cc) * 256;

    const f32x4 fz = {0.f, 0.f, 0.f, 0.f};
    f32x4 acc[2][4] = {{fz, fz, fz, fz}, {fz, fz, fz, fz}};
    #pragma unroll 4
    for (int kk = 0; kk < 256; kk += 32) {
        bf16x8 a0 = *(const bf16x8*)(wb0 + kk + 8 * g);
        bf16x8 a1 = *(const bf16x8*)(wb1 + kk + 8 * g);
        #pragma unroll
        for (int f = 0; f < 4; ++f) {
            bf16x8 bfr = *(const bf16x8*)(xb + (size_t)f * 16 * 256 + kk + 8 * g);
            acc[0][f] = __builtin_amdgcn_mfma_f32_16x16x32_bf16(a0, bfr, acc[0][f], 0, 0, 0);
            acc[1][f] = __builtin_amdgcn_mfma_f32_16x16x32_bf16(a1, bfr, acc[1][f], 0, 0, 0);
        }
    }

    const int head = by >> 1;
    const bool is_v = by & 1;
    float inv[2][4], bias[2][4];
    #pragma unroll
    for (int i = 0; i < 2; ++i) {
        #pragma unroll
        for (int r = 0; r < 4; ++r) {
            int oc = o_base + 16 * i + 4 * g + r;
            inv[i][r] = ivq[oc];
            bias[i][r] = bsq[oc];
        }
    }

    if (!is_v) {
        #pragma unroll
        for (int f = 0; f < 4; ++f) {
            int gl = gl0 + 16 * f + cc;
            int b  = gl / 1600;
            int ll = gl - b * 1600;
            unsigned short* dst = qk + ((size_t)(b * 4 + head) * 1600 + ll) * 64;
            #pragma unroll
            for (int i = 0; i < 2; ++i) {
                u16x4 pk;
                #pragma unroll
                for (int r = 0; r < 4; ++r) pk[r] = f2bf(acc[i][f][r] * inv[i][r] + bias[i][r]);
                *(u16x4*)(dst + (o_base & 63) + 16 * i + 4 * g) = pk;
            }
        }
    } else {
        const int d_base = (o_base & 63);
        // v2 (channel-major) stores + LDS transpose writes
        #pragma unroll
        for (int f = 0; f < 4; ++f) {
            int gl = gl0 + 16 * f + cc;
            unsigned short* v2dst = v2 + (size_t)gl * 256 + head * 64 + d_base;
            #pragma unroll
            for (int i = 0; i < 2; ++i) {
                u16x4 pk;
                #pragma unroll
                for (int r = 0; r < 4; ++r) {
                    unsigned short h = f2bf(acc[i][f][r] * inv[i][r] + bias[i][r]);
                    pk[r] = h;
                    ldsT[wid][(16 * i + 4 * g + r) * 72 + 16 * f + cc] = h;
                }
                *(u16x4*)(v2dst + 16 * i + 4 * g) = pk;
            }
        }
        asm volatile("s_waitcnt lgkmcnt(0)" ::: "memory");
        // coalesced vt stores: [d][l] rows, u16x8 per lane
        #pragma unroll
        for (int j = 0; j < 4; ++j) {
            int p = j * 64 + lane;
            int d_loc = p >> 3, c8 = p & 7;
            u16x8 val = *(const u16x8*)&ldsT[wid][d_loc * 72 + c8 * 8];
            int gl_c = gl0 + c8 * 8;
            int b  = gl_c / 1600;
            int ll = gl_c - b * 1600;
            *(u16x8*)(vt + ((size_t)(b * 4 + head) * 64 + d_base + d_loc) * 1600 + ll) = val;
        }
    }
}

// ---------- flash attention: block K-split, XCD-pinned combos, counted vmcnt ----------
// grid 1600: combo = bid&63 (pair*2+z), qt = bid>>6. 64%8==0 -> all 25 q-tiles
// of a combo land on XCD combo%8; per-XCD K/V/Q footprint ~3.2 MB (L2-resident).
__global__ __launch_bounds__(256) void attn_kernel(
    const unsigned short* __restrict__ qk, const unsigned short* __restrict__ vt,
    unsigned short* __restrict__ pa, unsigned short* __restrict__ pb,
    float* __restrict__ ssum)
{
    __shared__ __align__(16) unsigned short kbuf[2][64 * 32];  // [t][d], chunk^=(t&3)
    __shared__ __align__(16) unsigned short vbuf[2][64 * 64];  // [d][t], chunk^=(d&7)

    const int tid = threadIdx.x, wid = tid >> 6, lane = tid & 63;
    const int g = lane >> 4, cc = lane & 15;
    const int combo = blockIdx.x & 63;
    const int pair = combo >> 1;
    const int z = combo & 1;
    const int q0 = (blockIdx.x >> 6) * 64 + wid * 16;

    const int kt_begin = z ? 13 : 0;
    const int NT = z ? 12 : 13;

    const unsigned short* qkb = qk + (size_t)pair * 1600 * 64;
    const unsigned short* vtb = vt + (size_t)pair * 64 * 1600;

    bf16x8 bq = *(const bf16x8*)(qkb + (size_t)(q0 + cc) * 64 + 8 * g);

    // persistent staging source pointers (advance by constants per tile)
    const int krow = tid >> 2, kchk = tid & 3;
    const unsigned short* kP = qkb + (size_t)krow * 64 + 32 + (kchk ^ (krow & 3)) * 8
                              + (size_t)kt_begin * 4096;
    const int vrow = tid >> 3, vchk = tid & 7;
    const unsigned short* vPa = vtb + (size_t)vrow * 1600 + (vchk ^ (vrow & 7)) * 8
                              + (size_t)kt_begin * 64;
    const unsigned short* vPb = vPa + (size_t)32 * 1600;

    // precomputed LDS fragment base addresses (immediate offsets inside compute)
    const unsigned short* kr0  = &kbuf[0][cc * 32 + (g ^ (cc & 3)) * 8];
    const unsigned short* kr1  = &kbuf[1][cc * 32 + (g ^ (cc & 3)) * 8];
    const unsigned short* vr0a = &vbuf[0][cc * 64 + ((g) ^ (cc & 7)) * 8];
    const unsigned short* vr0b = &vbuf[0][cc * 64 + ((4 + g) ^ (cc & 7)) * 8];
    const unsigned short* vr1a = &vbuf[1][cc * 64 + ((g) ^ (cc & 7)) * 8];
    const unsigned short* vr1b = &vbuf[1][cc * 64 + ((4 + g) ^ (cc & 7)) * 8];

    #define STAGE(bufi)                                                               \
        do {                                                                          \
            __builtin_amdgcn_global_load_lds((g_u32*)kP,                              \
                (l_u32*)(&kbuf[bufi][wid * 512]), 16, 0, 0);                          \
            __builtin_amdgcn_global_load_lds((g_u32*)vPa,                             \
                (l_u32*)(&vbuf[bufi][wid * 512]), 16, 0, 0);                          \
            __builtin_amdgcn_global_load_lds((g_u32*)vPb,                             \
                (l_u32*)(&vbuf[bufi][2048 + wid * 512]), 16, 0, 0);                   \
            kP += 4096; vPa += 64; vPb += 64;                                         \
        } while (0)

    const f32x4 fz = {0.f, 0.f, 0.f, 0.f};
    const short one_bf = (short)0x3F80;
    const bf16x8 ones = {one_bf, one_bf, one_bf, one_bf, one_bf, one_bf, one_bf, one_bf};
    f32x4 o[4] = {fz, fz, fz, fz};
    f32x4 sumacc = fz;

    auto compute = [&](const unsigned short* kr, const unsigned short* vra,
                       const unsigned short* vrb) {
        bf16x8 kf[4], vf[8];
        #pragma unroll
        for (int f = 0; f < 4; ++f)
            kf[f] = *(const bf16x8*)(kr + f * 512);
        #pragma unroll
        for (int f2 = 0; f2 < 4; ++f2) {
            vf[2 * f2]     = *(const bf16x8*)(vra + f2 * 1024);
            vf[2 * f2 + 1] = *(const bf16x8*)(vrb + f2 * 1024);
        }

        // ---- QK^T ----
        f32x4 s4[4];
        __builtin_amdgcn_s_setprio(1);
        #pragma unroll
        for (int f = 0; f < 4; ++f)
            s4[f] = __builtin_amdgcn_mfma_f32_16x16x32_bf16(kf[f], bq, fz, 0, 0, 0);
        __builtin_amdgcn_s_setprio(0);

        // ---- exp2 (raw v_exp_f32) + pack + permlane transpose ----
        unsigned c2[4][2];
        #pragma unroll
        for (int f = 0; f < 4; ++f) {
            float p0 = __builtin_amdgcn_exp2f(s4[f][0]);
            float p1 = __builtin_amdgcn_exp2f(s4[f][1]);
            float p2 = __builtin_amdgcn_exp2f(s4[f][2]);
            float p3 = __builtin_amdgcn_exp2f(s4[f][3]);
            c2[f][0] = pkbf(p0, p1);
            c2[f][1] = pkbf(p2, p3);
        }
        unsigned pb_u[2][4];
        #pragma unroll
        for (int s2 = 0; s2 < 2; ++s2) {
            const int fA = 2 * s2, fB = 2 * s2 + 1;
            u32x2 xy0 = __builtin_amdgcn_permlane32_swap(c2[fA][0], c2[fB][0], false, false);
            u32x2 xy1 = __builtin_amdgcn_permlane32_swap(c2[fA][1], c2[fB][1], false, false);
            u32x2 w02 = __builtin_amdgcn_permlane16_swap(xy0.x, xy0.y, false, false);
            u32x2 w13 = __builtin_amdgcn_permlane16_swap(xy1.x, xy1.y, false, false);
            pb_u[s2][0] = w02.x;
            pb_u[s2][1] = w13.x;
            pb_u[s2][2] = w02.y;
            pb_u[s2][3] = w13.y;
        }

        // ---- PV + row-sum-by-ones ----
        __builtin_amdgcn_s_setprio(1);
        #pragma unroll
        for (int s2 = 0; s2 < 2; ++s2) {
            union { unsigned u[4]; bf16x8 v; } pbv;
            #pragma unroll
            for (int j = 0; j < 4; ++j) pbv.u[j] = pb_u[s2][j];
            #pragma unroll
            for (int f2 = 0; f2 < 4; ++f2)
                o[f2] = __builtin_amdgcn_mfma_f32_16x16x32_bf16(vf[f2 * 2 + s2], pbv.v, o[f2], 0, 0, 0);
            sumacc = __builtin_amdgcn_mfma_f32_16x16x32_bf16(ones, pbv.v, sumacc, 0, 0, 0);
        }
        __builtin_amdgcn_s_setprio(0);
    };

    // prologue: first tile -> buf0
    STAGE(0);

    // counted-vmcnt pipeline (generic parity loop; handles odd NT)
    for (int t = 0; t + 1 < NT; ++t) {
        STAGE((t + 1) & 1);                              // stage tile t+1
        asm volatile("s_waitcnt vmcnt(3)" ::: "memory"); // tile t's stage done
        __builtin_amdgcn_s_barrier();
        if (t & 1) compute(kr1, vr1a, vr1b);
        else       compute(kr0, vr0a, vr0b);
        __builtin_amdgcn_s_barrier();                    // all waves done with buf t&1
    }
    asm volatile("s_waitcnt vmcnt(0)" ::: "memory");
    __builtin_amdgcn_s_barrier();
    if ((NT - 1) & 1) compute(kr1, vr1a, vr1b);
    else              compute(kr0, vr0a, vr0b);
    #undef STAGE

    // ---- epilogue: store UNNORMALIZED partial O + per-q sums ----
    const int n = pair & 3, b = pair >> 2;
    unsigned short* pdst = (z ? pb : pa) + ((size_t)b * 1600 + q0 + cc) * 256 + n * 64;
    #pragma unroll
    for (int f2 = 0; f2 < 4; ++f2) {
        u16x4 st;
        #pragma unroll
        for (int r = 0; r < 4; ++r) st[r] = f2bf(o[f2][r]);
        *(u16x4*)(pdst + 16 * f2 + 4 * g) = st;
    }
    if (lane < 16)
        ssum[((size_t)z * 32 + b * 4 + n) * 1600 + q0 + cc] = sumacc[0];
}

// ---------- fused: y = (pa+pb)/sum; y2 = y + dw3x3(v, prescaled); out = cb2 GEMM ----------
// grid (400): per block 32 gl x 256 c. dw -> LDS [32][264], GEMM from LDS.
__global__ __launch_bounds__(256) void dwout_kernel(
    const unsigned short* __restrict__ v2,
    const unsigned short* __restrict__ pa, const unsigned short* __restrict__ pb,
    const float* __restrict__ ssum, const float* __restrict__ tab,
    const unsigned short* __restrict__ wcb,
    float* __restrict__ out)
{
    __shared__ unsigned short y2s[32][264];   // row stride 528B -> 2-way (free) on B reads

    const float* cwf  = tab + 1024;
    const float* bs1  = tab + 3328;
    const float* iv2t = tab + 3584;
    const float* bs2t = tab + 3840;

    const int tid = threadIdx.x, wid = tid >> 6, lane = tid & 63;
    const int g = lane >> 4, cc = lane & 15;
    const int gl0 = blockIdx.x * 32;

    // ---- dw + combine phase: 8 c-parts x 32 gl rows ----
    {
        const int gl_loc = tid & 31, cpart = tid >> 5;
        const int gl = gl0 + gl_loc;
        const int b = gl / 1600, l = gl - b * 1600;
        const int h = l / 40, w = l - h * 40;
        #pragma unroll
        for (int cg = 0; cg < 4; ++cg) {
            const int c0 = cpart * 32 + cg * 8;
            const int n = c0 >> 6;
            float s0 = ssum[(size_t)(b * 4 + n) * 1600 + l];
            float s1 = ssum[(size_t)(32 + b * 4 + n) * 1600 + l];
            float il = 1.f / (s0 + s1);
            float s[8];
            #pragma unroll
            for (int i = 0; i < 8; ++i) s[i] = 0.f;
            #pragma unroll
            for (int kh = -1; kh <= 1; ++kh) {
                int hh = h + kh;
                if (hh < 0 || hh >= 40) continue;
                #pragma unroll
                for (int kw = -1; kw <= 1; ++kw) {
                    int ww = w + kw;
                    if (ww < 0 || ww >= 40) continue;
                    u16x8 vv8 = *(const u16x8*)(v2 + (size_t)(gl + kh * 40 + kw) * 256 + c0);
                    const int tap = (kh + 1) * 3 + (kw + 1);
                    #pragma unroll
                    for (int i = 0; i < 8; ++i)
                        s[i] = fmaf(bf2f(vv8[i]), cwf[(c0 + i) * 9 + tap], s[i]);
                }
            }
            u16x8 ya = *(const u16x8*)(pa + (size_t)gl * 256 + c0);
            u16x8 yb = *(const u16x8*)(pb + (size_t)gl * 256 + c0);
            u16x8 o8;
            #pragma unroll
            for (int i = 0; i < 8; ++i) {
                int c = c0 + i;
                float yv = (bf2f(ya[i]) + bf2f(yb[i])) * il;
                o8[i] = f2bf(yv + s[i] + bs1[c]);
            }
            *(u16x8*)&y2s[gl_loc][c0] = o8;
        }
    }
    __syncthreads();

    // ---- GEMM phase: wave wid owns o in [wid*64, wid*64+64) ----
    const int o_base = wid * 64;
    const unsigned short* wb = wcb + (size_t)(o_base + cc) * 256;

    const f32x4 fz = {0.f, 0.f, 0.f, 0.f};
    f32x4 acc[4][2] = {{fz, fz}, {fz, fz}, {fz, fz}, {fz, fz}};
    #pragma unroll 4
    for (int kk = 0; kk < 256; kk += 32) {
        bf16x8 a[4], bfr[2];
        #pragma unroll
        for (int i = 0; i < 4; ++i)
            a[i] = *(const bf16x8*)(wb + (size_t)i * 16 * 256 + kk + 8 * g);
        #pragma unroll
        for (int f = 0; f < 2; ++f)
            bfr[f] = *(const bf16x8*)&y2s[16 * f + cc][kk + 8 * g];
        #pragma unroll
        for (int i = 0; i < 4; ++i)
            #pragma unroll
            for (int f = 0; f < 2; ++f)
                acc[i][f] = __builtin_amdgcn_mfma_f32_16x16x32_bf16(a[i], bfr[f], acc[i][f], 0, 0, 0);
    }
    #pragma unroll
    for (int i = 0; i < 4; ++i) {
        #pragma unroll
        for (int r = 0; r < 4; ++r) {
            int oc = o_base + 16 * i + 4 * g + r;
            float iv = iv2t[oc];
            float bs = bs2t[oc];
            #pragma unroll
            for (int f = 0; f < 2; ++f) {
                int gl = gl0 + 16 * f + cc;
                int b  = gl / 1600;
                int ll = gl - b * 1600;
                out[((size_t)b * 256 + oc) * 1600 + ll] = acc[i][f][r] * iv + bs;
            }
        }
    }
}

extern "C" void kernel_launch(void* const* d_in, const int* in_sizes, int n_in,
                              void* d_out, int out_size, void* d_ws, size_t ws_size,
                              hipStream_t stream) {
    const float* x     = (const float*)d_in[0];
    const float* qkv_w = (const float*)d_in[1];
    const float* qkv_g = (const float*)d_in[2];
    const float* qkv_b = (const float*)d_in[3];
    const float* qkv_m = (const float*)d_in[4];
    const float* qkv_v = (const float*)d_in[5];
    const float* cb1_w = (const float*)d_in[6];
    const float* cb1_g = (const float*)d_in[7];
    const float* cb1_b = (const float*)d_in[8];
    const float* cb1_m = (const float*)d_in[9];
    const float* cb1_v = (const float*)d_in[10];
    const float* cb2_w = (const float*)d_in[11];
    const float* cb2_g = (const float*)d_in[12];
    const float* cb2_b = (const float*)d_in[13];
    const float* cb2_m = (const float*)d_in[14];
    const float* cb2_v = (const float*)d_in[15];
    float* out = (float*)d_out;

    unsigned short* ws16 = (unsigned short*)d_ws;
    const size_t N16 = 3276800;                 // 8*1600*256
    unsigned short* xt  = ws16;                 // [gl][256]; reused as pa after qkv
    unsigned short* qk  = ws16 + N16;           // [pair][l][64]
    unsigned short* vt  = ws16 + 2 * N16;       // [pair][d][l]
    unsigned short* pb_ = ws16 + 3 * N16;       // [gl][256] partial O (half 1)
    unsigned short* v2  = ws16 + 4 * N16;       // [gl][256] v channel-major
    unsigned short* wqb = ws16 + 5 * N16;       // 512*256
    unsigned short* wcb = wqb + 131072;         // 256*256
    float* ssum = (float*)(wcb + 65536);        // [2][8][4][1600]
    float* tab  = ssum + 102400;                // BN tables (4096 floats)
    unsigned short* pa = xt;                    // alias (xt dead after qkv_gemm)

    conv_kernel<<<dim3(993), 256, 0, stream>>>(qkv_w, cb2_w, wqb, wcb, x, xt,
                                               qkv_g, qkv_b, qkv_m, qkv_v,
                                               cb1_w, cb1_g, cb1_b, cb1_m, cb1_v,
                                               cb2_g, cb2_b, cb2_m, cb2_v, tab);
    qkv_gemm_kernel<<<dim3(832), 256, 0, stream>>>(wqb, xt, tab, qk, vt, v2);
    attn_kernel<<<dim3(1600), 256, 0, stream>>>(qk, vt, pa, pb_, ssum);
    dwout_kernel<<<dim3(400), 256, 0, stream>>>(v2, pa, pb_, ssum, tab, wcb, out);
}

// Round 19
// 99.715 us; speedup vs baseline: 1.0744x; 1.0236x over previous
//
#include <hip/hip_runtime.h>
#include <hip/hip_bf16.h>

#define EPS 1e-3f
// 1/sqrt(32) * log2(e): scores come out of QK^T already in log2-space
#define QSC_LOG2E 0.2550348653f

typedef __attribute__((ext_vector_type(8))) short bf16x8;
typedef __attribute__((ext_vector_type(4))) float f32x4;
typedef __attribute__((ext_vector_type(4))) unsigned short u16x4;
typedef __attribute__((ext_vector_type(8))) unsigned short u16x8;
typedef __attribute__((ext_vector_type(2))) unsigned int u32x2;

typedef const __attribute__((address_space(1))) unsigned int g_u32;
typedef __attribute__((address_space(3))) unsigned int l_u32;

__device__ __forceinline__ unsigned short f2bf(float f) {
    union { float f; unsigned u; } v; v.f = f;
    unsigned r = v.u + 0x7FFFu + ((v.u >> 16) & 1u);
    return (unsigned short)(r >> 16);
}
__device__ __forceinline__ float bf2f(unsigned short h) {
    union { unsigned u; float f; } v; v.u = ((unsigned)h) << 16;
    return v.f;
}
__device__ __forceinline__ unsigned pkbf(float lo, float hi) {
    float2 t; t.x = lo; t.y = hi;
    __hip_bfloat162 h = __float22bfloat162_rn(t);
    union { __hip_bfloat162 h; unsigned u; } c; c.h = h;
    return c.u;
}

// ---------- fused: weights->bf16 (0..191) + BN tables (992) + x transpose (192..991) ----------
__global__ __launch_bounds__(256) void conv_kernel(
    const float* __restrict__ wq, const float* __restrict__ wc,
    unsigned short* __restrict__ wqb, unsigned short* __restrict__ wcb,
    const float* __restrict__ x, unsigned short* __restrict__ xt,
    const float* __restrict__ qg, const float* __restrict__ qb,
    const float* __restrict__ qm, const float* __restrict__ qv,
    const float* __restrict__ c1w, const float* __restrict__ c1g,
    const float* __restrict__ c1b, const float* __restrict__ c1m,
    const float* __restrict__ c1v,
    const float* __restrict__ c2g, const float* __restrict__ c2b,
    const float* __restrict__ c2m, const float* __restrict__ c2v,
    float* __restrict__ tab)
{
    int bid = blockIdx.x;
    int tid = threadIdx.x;
    if (bid < 192) {
        int i = (bid * 256 + tid) * 4;
        const float* src; unsigned short* dst; int off;
        if (i < 131072) { src = wq; dst = wqb; off = i; }
        else            { src = wc; dst = wcb; off = i - 131072; }
        f32x4 v = *(const f32x4*)(src + off);
        u16x4 o;
        #pragma unroll
        for (int j = 0; j < 4; ++j) o[j] = f2bf(v[j]);
        *(u16x4*)(dst + off) = o;
        return;
    }
    if (bid == 992) {
        // BN tables: ivq[512], bsq[512], cwf[2304], bs1[256], iv2t[256], bs2t[256]
        float* ivq  = tab;
        float* bsq  = tab + 512;
        float* cwf  = tab + 1024;
        float* bs1  = tab + 3328;
        float* iv2t = tab + 3584;
        float* bs2t = tab + 3840;
        for (int o = tid; o < 512; o += 256) {
            float iv = qg[o] * rsqrtf(qv[o] + EPS);
            float bs = qb[o] - qm[o] * iv;
            if ((o & 127) < 32) { iv *= QSC_LOG2E; bs *= QSC_LOG2E; }
            ivq[o] = iv; bsq[o] = bs;
        }
        {
            int c = tid;
            float iv1 = c1g[c] * rsqrtf(c1v[c] + EPS);
            bs1[c] = c1b[c] - c1m[c] * iv1;
            #pragma unroll
            for (int t = 0; t < 9; ++t) cwf[c * 9 + t] = c1w[c * 9 + t] * iv1;
            float iv2 = c2g[c] * rsqrtf(c2v[c] + EPS);
            iv2t[c] = iv2;
            bs2t[c] = c2b[c] - c2m[c] * iv2;
        }
        return;
    }
    __shared__ float t[64][65];
    int bid2 = bid - 192;
    int l0 = (bid2 % 25) * 64, c0 = ((bid2 / 25) & 3) * 64, b = bid2 / 100;
    const float* xb = x + ((size_t)b * 256 + c0) * 1600 + l0;
    #pragma unroll
    for (int p = 0; p < 4; ++p) {
        int row = p * 16 + (tid >> 4);
        int col = (tid & 15) * 4;
        f32x4 v = *(const f32x4*)(xb + (size_t)row * 1600 + col);
        #pragma unroll
        for (int j = 0; j < 4; ++j) t[row][col + j] = v[j];
    }
    __syncthreads();
    int l = tid >> 2, cs = tid & 3;
    u16x8 o0, o1;
    #pragma unroll
    for (int i = 0; i < 8; ++i) o0[i] = f2bf(t[cs * 16 + i][l]);
    #pragma unroll
    for (int i = 0; i < 8; ++i) o1[i] = f2bf(t[cs * 16 + 8 + i][l]);
    unsigned short* dst = xt + ((size_t)b * 1600 + l0 + l) * 256 + c0 + cs * 16;
    *(u16x8*)dst = o0;
    *(u16x8*)(dst + 8) = o1;
}

// ---------- qkv = BN(qkv_w @ x) via MFMA, 32o x 64l per wave ----------
// grid 832 (XCD-pinned): o_tile = bid/104, gl_tile = bid%104 (<100).
__global__ __launch_bounds__(256) void qkv_gemm_kernel(
    const unsigned short* __restrict__ wqb, const unsigned short* __restrict__ xt,
    const float* __restrict__ tab,
    unsigned short* __restrict__ qk, unsigned short* __restrict__ vt,
    unsigned short* __restrict__ v2)
{
    __shared__ unsigned short ldsT[4][32 * 72];   // per-wave transpose tile [d_loc][l_loc]

    const int gl_tile = blockIdx.x % 104;
    const int by = blockIdx.x / 104;
    if (gl_tile >= 100) return;                   // safe: no barriers before this point

    const float* ivq = tab;
    const float* bsq = tab + 512;

    const int tid = threadIdx.x, wid = tid >> 6, lane = tid & 63;
    const int g = lane >> 4, cc = lane & 15;
    const int gl0 = gl_tile * 128 + (wid & 1) * 64;
    const int o_base = by * 64 + (wid >> 1) * 32;

    const unsigned short* wb0 = wqb + (size_t)(o_base + cc) * 256;
    const unsigned short* wb1 = wqb + (size_t)(o_base + 16 + cc) * 256;
    const unsigned short* xb  = xt + (size_t)(gl0 + cc) * 256;

    const f32x4 fz = {0.f, 0.f, 0.f, 0.f};
    f32x4 acc[2][4] = {{fz, fz, fz, fz}, {fz, fz, fz, fz}};
    #pragma unroll 4
    for (int kk = 0; kk < 256; kk += 32) {
        bf16x8 a0 = *(const bf16x8*)(wb0 + kk + 8 * g);
        bf16x8 a1 = *(const bf16x8*)(wb1 + kk + 8 * g);
        #pragma unroll
        for (int f = 0; f < 4; ++f) {
            bf16x8 bfr = *(const bf16x8*)(xb + (size_t)f * 16 * 256 + kk + 8 * g);
            acc[0][f] = __builtin_amdgcn_mfma_f32_16x16x32_bf16(a0, bfr, acc[0][f], 0, 0, 0);
            acc[1][f] = __builtin_amdgcn_mfma_f32_16x16x32_bf16(a1, bfr, acc[1][f], 0, 0, 0);
        }
    }

    const int head = by >> 1;
    const bool is_v = by & 1;
    float inv[2][4], bias[2][4];
    #pragma unroll
    for (int i = 0; i < 2; ++i) {
        #pragma unroll
        for (int r = 0; r < 4; ++r) {
            int oc = o_base + 16 * i + 4 * g + r;
            inv[i][r] = ivq[oc];
            bias[i][r] = bsq[oc];
        }
    }

    if (!is_v) {
        #pragma unroll
        for (int f = 0; f < 4; ++f) {
            int gl = gl0 + 16 * f + cc;
            int b  = gl / 1600;
            int ll = gl - b * 1600;
            unsigned short* dst = qk + ((size_t)(b * 4 + head) * 1600 + ll) * 64;
            #pragma unroll
            for (int i = 0; i < 2; ++i) {
                u16x4 pk;
                #pragma unroll
                for (int r = 0; r < 4; ++r) pk[r] = f2bf(acc[i][f][r] * inv[i][r] + bias[i][r]);
                *(u16x4*)(dst + (o_base & 63) + 16 * i + 4 * g) = pk;
            }
        }
    } else {
        const int d_base = (o_base & 63);
        // v2 (channel-major) stores + LDS transpose writes
        #pragma unroll
        for (int f = 0; f < 4; ++f) {
            int gl = gl0 + 16 * f + cc;
            unsigned short* v2dst = v2 + (size_t)gl * 256 + head * 64 + d_base;
            #pragma unroll
            for (int i = 0; i < 2; ++i) {
                u16x4 pk;
                #pragma unroll
                for (int r = 0; r < 4; ++r) {
                    unsigned short h = f2bf(acc[i][f][r] * inv[i][r] + bias[i][r]);
                    pk[r] = h;
                    ldsT[wid][(16 * i + 4 * g + r) * 72 + 16 * f + cc] = h;
                }
                *(u16x4*)(v2dst + 16 * i + 4 * g) = pk;
            }
        }
        asm volatile("s_waitcnt lgkmcnt(0)" ::: "memory");
        // coalesced vt stores: [d][l] rows, u16x8 per lane
        #pragma unroll
        for (int j = 0; j < 4; ++j) {
            int p = j * 64 + lane;
            int d_loc = p >> 3, c8 = p & 7;
            u16x8 val = *(const u16x8*)&ldsT[wid][d_loc * 72 + c8 * 8];
            int gl_c = gl0 + c8 * 8;
            int b  = gl_c / 1600;
            int ll = gl_c - b * 1600;
            *(u16x8*)(vt + ((size_t)(b * 4 + head) * 64 + d_base + d_loc) * 1600 + ll) = val;
        }
    }
}

// ---------- flash attention: block K-split, XCD-pinned combos, counted vmcnt ----------
// grid 1600: combo = bid&63 (pair*2+z), qt = bid>>6. 64%8==0 -> all 25 q-tiles
// of a combo land on XCD combo%8; per-XCD K/V/Q footprint ~3.2 MB (L2-resident).
// Lockstep barrier structure -> no s_setprio (T5 null/harmful in lockstep, m190).
__global__ __launch_bounds__(256) void attn_kernel(
    const unsigned short* __restrict__ qk, const unsigned short* __restrict__ vt,
    unsigned short* __restrict__ pa, unsigned short* __restrict__ pb,
    float* __restrict__ ssum)
{
    __shared__ __align__(16) unsigned short kbuf[2][64 * 32];  // [t][d], chunk^=(t&3)
    __shared__ __align__(16) unsigned short vbuf[2][64 * 64];  // [d][t], chunk^=(d&7)

    const int tid = threadIdx.x, wid = tid >> 6, lane = tid & 63;
    const int g = lane >> 4, cc = lane & 15;
    const int combo = blockIdx.x & 63;
    const int pair = combo >> 1;
    const int z = combo & 1;
    const int q0 = (blockIdx.x >> 6) * 64 + wid * 16;

    const int kt_begin = z ? 13 : 0;
    const int NT = z ? 12 : 13;

    const unsigned short* qkb = qk + (size_t)pair * 1600 * 64;
    const unsigned short* vtb = vt + (size_t)pair * 64 * 1600;

    bf16x8 bq = *(const bf16x8*)(qkb + (size_t)(q0 + cc) * 64 + 8 * g);

    // persistent staging source pointers (advance by constants per tile)
    const int krow = tid >> 2, kchk = tid & 3;
    const unsigned short* kP = qkb + (size_t)krow * 64 + 32 + (kchk ^ (krow & 3)) * 8
                              + (size_t)kt_begin * 4096;
    const int vrow = tid >> 3, vchk = tid & 7;
    const unsigned short* vPa = vtb + (size_t)vrow * 1600 + (vchk ^ (vrow & 7)) * 8
                              + (size_t)kt_begin * 64;
    const unsigned short* vPb = vPa + (size_t)32 * 1600;

    // precomputed LDS fragment base addresses (immediate offsets inside compute)
    const unsigned short* kr0  = &kbuf[0][cc * 32 + (g ^ (cc & 3)) * 8];
    const unsigned short* kr1  = &kbuf[1][cc * 32 + (g ^ (cc & 3)) * 8];
    const unsigned short* vr0a = &vbuf[0][cc * 64 + ((g) ^ (cc & 7)) * 8];
    const unsigned short* vr0b = &vbuf[0][cc * 64 + ((4 + g) ^ (cc & 7)) * 8];
    const unsigned short* vr1a = &vbuf[1][cc * 64 + ((g) ^ (cc & 7)) * 8];
    const unsigned short* vr1b = &vbuf[1][cc * 64 + ((4 + g) ^ (cc & 7)) * 8];

    #define STAGE(bufi)                                                               \
        do {                                                                          \
            __builtin_amdgcn_global_load_lds((g_u32*)kP,                              \
                (l_u32*)(&kbuf[bufi][wid * 512]), 16, 0, 0);                          \
            __builtin_amdgcn_global_load_lds((g_u32*)vPa,                             \
                (l_u32*)(&vbuf[bufi][wid * 512]), 16, 0, 0);                          \
            __builtin_amdgcn_global_load_lds((g_u32*)vPb,                             \
                (l_u32*)(&vbuf[bufi][2048 + wid * 512]), 16, 0, 0);                   \
            kP += 4096; vPa += 64; vPb += 64;                                         \
        } while (0)

    const f32x4 fz = {0.f, 0.f, 0.f, 0.f};
    const short one_bf = (short)0x3F80;
    const bf16x8 ones = {one_bf, one_bf, one_bf, one_bf, one_bf, one_bf, one_bf, one_bf};
    f32x4 o[4] = {fz, fz, fz, fz};
    f32x4 sumacc = fz;

    auto compute = [&](const unsigned short* kr, const unsigned short* vra,
                       const unsigned short* vrb) {
        bf16x8 kf[4], vf[8];
        #pragma unroll
        for (int f = 0; f < 4; ++f)
            kf[f] = *(const bf16x8*)(kr + f * 512);
        #pragma unroll
        for (int f2 = 0; f2 < 4; ++f2) {
            vf[2 * f2]     = *(const bf16x8*)(vra + f2 * 1024);
            vf[2 * f2 + 1] = *(const bf16x8*)(vrb + f2 * 1024);
        }

        // ---- QK^T ----
        f32x4 s4[4];
        #pragma unroll
        for (int f = 0; f < 4; ++f)
            s4[f] = __builtin_amdgcn_mfma_f32_16x16x32_bf16(kf[f], bq, fz, 0, 0, 0);

        // ---- exp2 (raw v_exp_f32) + pack + permlane transpose ----
        unsigned c2[4][2];
        #pragma unroll
        for (int f = 0; f < 4; ++f) {
            float p0 = __builtin_amdgcn_exp2f(s4[f][0]);
            float p1 = __builtin_amdgcn_exp2f(s4[f][1]);
            float p2 = __builtin_amdgcn_exp2f(s4[f][2]);
            float p3 = __builtin_amdgcn_exp2f(s4[f][3]);
            c2[f][0] = pkbf(p0, p1);
            c2[f][1] = pkbf(p2, p3);
        }
        unsigned pb_u[2][4];
        #pragma unroll
        for (int s2 = 0; s2 < 2; ++s2) {
            const int fA = 2 * s2, fB = 2 * s2 + 1;
            u32x2 xy0 = __builtin_amdgcn_permlane32_swap(c2[fA][0], c2[fB][0], false, false);
            u32x2 xy1 = __builtin_amdgcn_permlane32_swap(c2[fA][1], c2[fB][1], false, false);
            u32x2 w02 = __builtin_amdgcn_permlane16_swap(xy0.x, xy0.y, false, false);
            u32x2 w13 = __builtin_amdgcn_permlane16_swap(xy1.x, xy1.y, false, false);
            pb_u[s2][0] = w02.x;
            pb_u[s2][1] = w13.x;
            pb_u[s2][2] = w02.y;
            pb_u[s2][3] = w13.y;
        }

        // ---- PV + row-sum-by-ones ----
        #pragma unroll
        for (int s2 = 0; s2 < 2; ++s2) {
            union { unsigned u[4]; bf16x8 v; } pbv;
            #pragma unroll
            for (int j = 0; j < 4; ++j) pbv.u[j] = pb_u[s2][j];
            #pragma unroll
            for (int f2 = 0; f2 < 4; ++f2)
                o[f2] = __builtin_amdgcn_mfma_f32_16x16x32_bf16(vf[f2 * 2 + s2], pbv.v, o[f2], 0, 0, 0);
            sumacc = __builtin_amdgcn_mfma_f32_16x16x32_bf16(ones, pbv.v, sumacc, 0, 0, 0);
        }
    };

    // prologue: first tile -> buf0
    STAGE(0);

    // counted-vmcnt pipeline (generic parity loop; handles odd NT)
    for (int t = 0; t + 1 < NT; ++t) {
        STAGE((t + 1) & 1);                              // stage tile t+1
        asm volatile("s_waitcnt vmcnt(3)" ::: "memory"); // tile t's stage done
        __builtin_amdgcn_s_barrier();
        if (t & 1) compute(kr1, vr1a, vr1b);
        else       compute(kr0, vr0a, vr0b);
        __builtin_amdgcn_s_barrier();                    // all waves done with buf t&1
    }
    asm volatile("s_waitcnt vmcnt(0)" ::: "memory");
    __builtin_amdgcn_s_barrier();
    if ((NT - 1) & 1) compute(kr1, vr1a, vr1b);
    else              compute(kr0, vr0a, vr0b);
    #undef STAGE

    // ---- epilogue: store UNNORMALIZED partial O + per-q sums ----
    const int n = pair & 3, b = pair >> 2;
    unsigned short* pdst = (z ? pb : pa) + ((size_t)b * 1600 + q0 + cc) * 256 + n * 64;
    #pragma unroll
    for (int f2 = 0; f2 < 4; ++f2) {
        u16x4 st;
        #pragma unroll
        for (int r = 0; r < 4; ++r) st[r] = f2bf(o[f2][r]);
        *(u16x4*)(pdst + 16 * f2 + 4 * g) = st;
    }
    if (lane < 16)
        ssum[((size_t)z * 32 + b * 4 + n) * 1600 + q0 + cc] = sumacc[0];
}

// ---------- fused: y = (pa+pb)/sum; y2 = y + dw3x3(v, prescaled); out = cb2 GEMM ----------
// grid (400): per block 32 gl x 256 c. dw -> LDS [32][264], GEMM from LDS.
__global__ __launch_bounds__(256) void dwout_kernel(
    const unsigned short* __restrict__ v2,
    const unsigned short* __restrict__ pa, const unsigned short* __restrict__ pb,
    const float* __restrict__ ssum, const float* __restrict__ tab,
    const unsigned short* __restrict__ wcb,
    float* __restrict__ out)
{
    __shared__ unsigned short y2s[32][264];   // row stride 528B -> 2-way (free) on B reads

    const float* cwf  = tab + 1024;
    const float* bs1  = tab + 3328;
    const float* iv2t = tab + 3584;
    const float* bs2t = tab + 3840;

    const int tid = threadIdx.x, wid = tid >> 6, lane = tid & 63;
    const int g = lane >> 4, cc = lane & 15;
    const int gl0 = blockIdx.x * 32;

    // ---- dw + combine phase: 8 c-parts x 32 gl rows ----
    {
        const int gl_loc = tid & 31, cpart = tid >> 5;
        const int gl = gl0 + gl_loc;
        const int b = gl / 1600, l = gl - b * 1600;
        const int h = l / 40, w = l - h * 40;
        #pragma unroll
        for (int cg = 0; cg < 4; ++cg) {
            const int c0 = cpart * 32 + cg * 8;
            const int n = c0 >> 6;
            float s0 = ssum[(size_t)(b * 4 + n) * 1600 + l];
            float s1 = ssum[(size_t)(32 + b * 4 + n) * 1600 + l];
            float il = 1.f / (s0 + s1);
            float s[8];
            #pragma unroll
            for (int i = 0; i < 8; ++i) s[i] = 0.f;
            #pragma unroll
            for (int kh = -1; kh <= 1; ++kh) {
                int hh = h + kh;
                if (hh < 0 || hh >= 40) continue;
                #pragma unroll
                for (int kw = -1; kw <= 1; ++kw) {
                    int ww = w + kw;
                    if (ww < 0 || ww >= 40) continue;
                    u16x8 vv8 = *(const u16x8*)(v2 + (size_t)(gl + kh * 40 + kw) * 256 + c0);
                    const int tap = (kh + 1) * 3 + (kw + 1);
                    #pragma unroll
                    for (int i = 0; i < 8; ++i)
                        s[i] = fmaf(bf2f(vv8[i]), cwf[(c0 + i) * 9 + tap], s[i]);
                }
            }
            u16x8 ya = *(const u16x8*)(pa + (size_t)gl * 256 + c0);
            u16x8 yb = *(const u16x8*)(pb + (size_t)gl * 256 + c0);
            u16x8 o8;
            #pragma unroll
            for (int i = 0; i < 8; ++i) {
                int c = c0 + i;
                float yv = (bf2f(ya[i]) + bf2f(yb[i])) * il;
                o8[i] = f2bf(yv + s[i] + bs1[c]);
            }
            *(u16x8*)&y2s[gl_loc][c0] = o8;
        }
    }
    __syncthreads();

    // ---- GEMM phase: wave wid owns o in [wid*64, wid*64+64) ----
    const int o_base = wid * 64;
    const unsigned short* wb = wcb + (size_t)(o_base + cc) * 256;

    const f32x4 fz = {0.f, 0.f, 0.f, 0.f};
    f32x4 acc[4][2] = {{fz, fz}, {fz, fz}, {fz, fz}, {fz, fz}};
    #pragma unroll 4
    for (int kk = 0; kk < 256; kk += 32) {
        bf16x8 a[4], bfr[2];
        #pragma unroll
        for (int i = 0; i < 4; ++i)
            a[i] = *(const bf16x8*)(wb + (size_t)i * 16 * 256 + kk + 8 * g);
        #pragma unroll
        for (int f = 0; f < 2; ++f)
            bfr[f] = *(const bf16x8*)&y2s[16 * f + cc][kk + 8 * g];
        #pragma unroll
        for (int i = 0; i < 4; ++i)
            #pragma unroll
            for (int f = 0; f < 2; ++f)
                acc[i][f] = __builtin_amdgcn_mfma_f32_16x16x32_bf16(a[i], bfr[f], acc[i][f], 0, 0, 0);
    }
    #pragma unroll
    for (int i = 0; i < 4; ++i) {
        #pragma unroll
        for (int r = 0; r < 4; ++r) {
            int oc = o_base + 16 * i + 4 * g + r;
            float iv = iv2t[oc];
            float bs = bs2t[oc];
            #pragma unroll
            for (int f = 0; f < 2; ++f) {
                int gl = gl0 + 16 * f + cc;
                int b  = gl / 1600;
                int ll = gl - b * 1600;
                out[((size_t)b * 256 + oc) * 1600 + ll] = acc[i][f][r] * iv + bs;
            }
        }
    }
}

extern "C" void kernel_launch(void* const* d_in, const int* in_sizes, int n_in,
                              void* d_out, int out_size, void* d_ws, size_t ws_size,
                              hipStream_t stream) {
    const float* x     = (const float*)d_in[0];
    const float* qkv_w = (const float*)d_in[1];
    const float* qkv_g = (const float*)d_in[2];
    const float* qkv_b = (const float*)d_in[3];
    const float* qkv_m = (const float*)d_in[4];
    const float* qkv_v = (const float*)d_in[5];
    const float* cb1_w = (const float*)d_in[6];
    const float* cb1_g = (const float*)d_in[7];
    const float* cb1_b = (const float*)d_in[8];
    const float* cb1_m = (const float*)d_in[9];
    const float* cb1_v = (const float*)d_in[10];
    const float* cb2_w = (const float*)d_in[11];
    const float* cb2_g = (const float*)d_in[12];
    const float* cb2_b = (const float*)d_in[13];
    const float* cb2_m = (const float*)d_in[14];
    const float* cb2_v = (const float*)d_in[15];
    float* out = (float*)d_out;

    unsigned short* ws16 = (unsigned short*)d_ws;
    const size_t N16 = 3276800;                 // 8*1600*256
    unsigned short* xt  = ws16;                 // [gl][256]; reused as pa after qkv
    unsigned short* qk  = ws16 + N16;           // [pair][l][64]
    unsigned short* vt  = ws16 + 2 * N16;       // [pair][d][l]
    unsigned short* pb_ = ws16 + 3 * N16;       // [gl][256] partial O (half 1)
    unsigned short* v2  = ws16 + 4 * N16;       // [gl][256] v channel-major
    unsigned short* wqb = ws16 + 5 * N16;       // 512*256
    unsigned short* wcb = wqb + 131072;         // 256*256
    float* ssum = (float*)(wcb + 65536);        // [2][8][4][1600]
    float* tab  = ssum + 102400;                // BN tables (4096 floats)
    unsigned short* pa = xt;                    // alias (xt dead after qkv_gemm)

    conv_kernel<<<dim3(993), 256, 0, stream>>>(qkv_w, cb2_w, wqb, wcb, x, xt,
                                               qkv_g, qkv_b, qkv_m, qkv_v,
                                               cb1_w, cb1_g, cb1_b, cb1_m, cb1_v,
                                               cb2_g, cb2_b, cb2_m, cb2_v, tab);
    qkv_gemm_kernel<<<dim3(832), 256, 0, stream>>>(wqb, xt, tab, qk, vt, v2);
    attn_kernel<<<dim3(1600), 256, 0, stream>>>(qk, vt, pa, pb_, ssum);
    dwout_kernel<<<dim3(400), 256, 0, stream>>>(v2, pa, pb_, ssum, tab, wcb, out);
}